// Round 1
// baseline (3966.960 us; speedup 1.0000x reference)
//
#include <hip/hip_runtime.h>
#include <hip/hip_bf16.h>
#include <stdint.h>

#define TILE 32

__device__ __forceinline__ float bflo(uint32_t p){ union{uint32_t u;float f;}v; v.u = p << 16; return v.f; }
__device__ __forceinline__ float bfhi(uint32_t p){ union{uint32_t u;float f;}v; v.u = p & 0xffff0000u; return v.f; }
__device__ __forceinline__ uint16_t f2bf(float f){
    union{float f;uint32_t u;}v; v.f = f;
    return (uint16_t)((v.u + 0x7fffu + ((v.u >> 16) & 1u)) >> 16);  // RNE
}
__device__ __forceinline__ float fsigmoid(float x){ return 1.0f / (1.0f + __expf(-x)); }
__device__ __forceinline__ float fsilu(float x){ return x * fsigmoid(x); }

// LDS layout (51200 B total, 3 blocks/CU):
//  [0..16384)      hf   f32[32][128]  pre-LN scratch   | later: nsrc bf16[32][128] @0, ndst @8192
//  [16384..24576)  bufA bf16[32][128] LN1-out, later e3
//  [24576..32768)  bufB bf16[32][128] LN2-out, later din (dual input)
//  [32768..49152)  hd1  bf16[32][256] d1-out, later x1
//  [49152..51200)  misc: a16 f32[512] (be1 input) OVERLAPPED (disjoint lifetime) with
//                  mu[32],rs[32],dp[32],ps[32],pd[32],red[64],sidx[32],didx[32]

extern "C" __global__ void __launch_bounds__(256, 3)
bondpred_kernel(const float* __restrict__ node_emb,
                const int*   __restrict__ edge_index,
                const float* __restrict__ edge_attr,
                const float* __restrict__ dual_emb,
                const float* __restrict__ logits,
                const float* __restrict__ W_be1, const float* __restrict__ b_be1,
                const float* __restrict__ g_be1, const float* __restrict__ bb_be1,
                const float* __restrict__ W_be2, const float* __restrict__ b_be2,
                const float* __restrict__ g_be2, const float* __restrict__ bb_be2,
                const float* __restrict__ W_be3, const float* __restrict__ b_be3,
                const float* __restrict__ g_be3, const float* __restrict__ bb_be3,
                const float* __restrict__ W_d1, const float* __restrict__ b_d1,
                const float* __restrict__ W_d2, const float* __restrict__ b_d2,
                const float* __restrict__ W_do, const float* __restrict__ b_do,
                const float* __restrict__ W_f1, const float* __restrict__ b_f1,
                const float* __restrict__ W_f2, const float* __restrict__ b_f2,
                const float* __restrict__ W_bo, const float* __restrict__ b_bo,
                float* __restrict__ out, int E)
{
    __shared__ char lds[51200];
    float*    hf     = (float*)lds;
    uint16_t* nsrc   = (uint16_t*)lds;
    uint32_t* nsrc32 = (uint32_t*)lds;
    uint16_t* ndst   = (uint16_t*)(lds + 8192);
    uint32_t* ndst32 = (uint32_t*)(lds + 8192);
    uint16_t* bufA   = (uint16_t*)(lds + 16384);
    uint32_t* bufA32 = (uint32_t*)(lds + 16384);
    uint16_t* bufB   = (uint16_t*)(lds + 24576);
    uint32_t* bufB32 = (uint32_t*)(lds + 24576);
    uint16_t* hd1    = (uint16_t*)(lds + 32768);
    uint32_t* hd132  = (uint32_t*)(lds + 32768);
    float* a16 = (float*)(lds + 49152);
    float* mu  = (float*)(lds + 49152);
    float* rs  = (float*)(lds + 49280);
    float* dp  = (float*)(lds + 49408);
    float* ps  = (float*)(lds + 49536);
    float* pd  = (float*)(lds + 49664);
    float* red = (float*)(lds + 49792);   // f32[4][16]
    int* sidx  = (int*)(lds + 50048);
    int* didx  = (int*)(lds + 50176);

    const int tid   = threadIdx.x;
    const int j0    = tid & 127;
    const int eh    = tid >> 7;      // edge-half: 0 -> edges 0..15, 1 -> 16..31
    const int lane  = tid & 63;
    const int wid   = tid >> 6;
    const int e0    = blockIdx.x * TILE;
    const int ebase = eh * 16;

    // ---- phase 1: load edge_attr tile (32x16 f32, contiguous) ----
    {
        int lim = E * 16;
        int i0 = e0 * 16 + tid;
        int i1 = i0 + 256;
        a16[tid]       = edge_attr[i0 < lim ? i0 : lim - 1];
        a16[tid + 256] = edge_attr[i1 < lim ? i1 : lim - 1];
    }
    __syncthreads();

    float acc[16], acc0[16], acc1[16];

    auto ln_reduce = [&]() {
        #pragma unroll
        for (int r = 0; r < 8; ++r) {
            int e = wid * 8 + r;
            float v0 = hf[e * 128 + lane];
            float v1 = hf[e * 128 + 64 + lane];
            float s = v0 + v1;
            float q = v0 * v0 + v1 * v1;
            #pragma unroll
            for (int off = 32; off; off >>= 1) {
                s += __shfl_xor(s, off);
                q += __shfl_xor(q, off);
            }
            if (lane == 0) {
                float m = s * 0.0078125f;                 // /128
                float var = q * 0.0078125f - m * m;
                mu[e] = m;
                rs[e] = rsqrtf(var + 1e-5f);
            }
        }
    };

    auto ln_apply = [&](const float* g, const float* bb, uint16_t* dstb) {
        float gg = g[j0], bv = bb[j0];
        #pragma unroll
        for (int e = 0; e < 16; ++e) {
            int ge = ebase + e;
            float v = (hf[ge * 128 + j0] - mu[ge]) * rs[ge] * gg + bv;
            dstb[ge * 128 + j0] = f2bf(fsilu(v));
        }
    };

    auto mm128 = [&](const uint32_t* inb, const float* W, const float* b) {
        float bv = b[j0];
        #pragma unroll
        for (int e = 0; e < 16; ++e) acc[e] = bv;
        #pragma unroll 2
        for (int k2 = 0; k2 < 64; ++k2) {
            float w0 = W[(2 * k2) * 128 + j0];
            float w1 = W[(2 * k2 + 1) * 128 + j0];
            const uint32_t* ir = inb + ebase * 64 + k2;
            #pragma unroll
            for (int e = 0; e < 16; ++e) {
                uint32_t p = ir[e * 64];
                acc[e] = fmaf(bflo(p), w0, acc[e]);
                acc[e] = fmaf(bfhi(p), w1, acc[e]);
            }
        }
        #pragma unroll
        for (int e = 0; e < 16; ++e) hf[(ebase + e) * 128 + j0] = acc[e];
    };

    // 256-wide layer segment: thread owns columns {j0, j0+128}, accumulates into acc0/acc1
    auto mm256seg = [&](const uint32_t* inb, int K2, const float* W) {
        #pragma unroll 2
        for (int k2 = 0; k2 < K2; ++k2) {
            const float* Wr = W + (2 * k2) * 256;
            float w00 = Wr[j0],       w01 = Wr[j0 + 128];
            float w10 = Wr[256 + j0], w11 = Wr[256 + j0 + 128];
            const uint32_t* ir = inb + ebase * K2 + k2;
            #pragma unroll
            for (int e = 0; e < 16; ++e) {
                uint32_t p = ir[e * K2];
                float lo = bflo(p), hi = bfhi(p);
                acc0[e] = fmaf(lo, w00, acc0[e]);
                acc0[e] = fmaf(hi, w10, acc0[e]);
                acc1[e] = fmaf(lo, w01, acc1[e]);
                acc1[e] = fmaf(hi, w11, acc1[e]);
            }
        }
    };

    // ---- bond embedding layer 1 (K=16, f32 input) ----
    {
        float bv = b_be1[j0];
        #pragma unroll
        for (int e = 0; e < 16; ++e) acc[e] = bv;
        #pragma unroll
        for (int k = 0; k < 16; ++k) {
            float w = W_be1[k * 128 + j0];
            const float* ar = a16 + ebase * 16 + k;
            #pragma unroll
            for (int e = 0; e < 16; ++e) acc[e] = fmaf(ar[e * 16], w, acc[e]);
        }
        #pragma unroll
        for (int e = 0; e < 16; ++e) hf[(ebase + e) * 128 + j0] = acc[e];
    }
    __syncthreads();
    ln_reduce(); __syncthreads();
    ln_apply(g_be1, bb_be1, bufA); __syncthreads();

    // ---- bond embedding layers 2,3 ----
    mm128(bufA32, W_be2, b_be2); __syncthreads();
    ln_reduce(); __syncthreads();
    ln_apply(g_be2, bb_be2, bufB); __syncthreads();

    mm128(bufB32, W_be3, b_be3); __syncthreads();
    ln_reduce(); __syncthreads();
    ln_apply(g_be3, bb_be3, bufA); __syncthreads();   // e3 lives in bufA

    // ---- gather: indices, p_src/p_dst, node embeddings, dual input ----
    if (tid < 32) {
        int ge = e0 + tid; if (ge >= E) ge = E - 1;
        int s_ = edge_index[ge];
        int d_ = edge_index[E + ge];
        sidx[tid] = s_; didx[tid] = d_;
        ps[tid] = fsigmoid(logits[s_]);
        pd[tid] = fsigmoid(logits[d_]);
    }
    __syncthreads();
    {
        #pragma unroll
        for (int it = 0; it < 16; ++it) {
            int e = it * 2 + eh;
            nsrc[e * 128 + j0] = f2bf(node_emb[sidx[e] * 128 + j0]);
            ndst[e * 128 + j0] = f2bf(node_emb[didx[e] * 128 + j0]);
        }
        int lim = E * 128;
        int base = e0 * 128;
        #pragma unroll
        for (int r = 0; r < 16; ++r) {
            int i = r * 256 + tid;
            int gi = base + i;
            bufB[i] = f2bf(dual_emb[gi < lim ? gi : lim - 1]);   // din overwrites bufB
        }
    }
    __syncthreads();

    // ---- dual layer 1: 128 -> 256 ----
    {
        float b0 = b_d1[j0], b1 = b_d1[j0 + 128];
        #pragma unroll
        for (int e = 0; e < 16; ++e) { acc0[e] = b0; acc1[e] = b1; }
        mm256seg(bufB32, 64, W_d1);
        #pragma unroll
        for (int e = 0; e < 16; ++e) {
            int ge = ebase + e;
            hd1[ge * 256 + j0]       = f2bf(fsilu(acc0[e]));
            hd1[ge * 256 + 128 + j0] = f2bf(fsilu(acc1[e]));
        }
    }
    __syncthreads();

    // ---- dual layer 2 (256 -> 256) fused with W_do dot + sigmoid ----
    {
        float b0 = b_d2[j0], b1 = b_d2[j0 + 128];
        #pragma unroll
        for (int e = 0; e < 16; ++e) { acc0[e] = b0; acc1[e] = b1; }
        mm256seg(hd132, 128, W_d2);
        float w0 = W_do[j0], w1 = W_do[j0 + 128];
        float part[16];
        #pragma unroll
        for (int e = 0; e < 16; ++e)
            part[e] = fsilu(acc0[e]) * w0 + fsilu(acc1[e]) * w1;
        #pragma unroll
        for (int off = 32; off; off >>= 1) {
            #pragma unroll
            for (int e = 0; e < 16; ++e) part[e] += __shfl_xor(part[e], off);
        }
        if (lane == 0) {
            #pragma unroll
            for (int e = 0; e < 16; ++e) red[wid * 16 + e] = part[e];
        }
    }
    __syncthreads();
    if (tid < 32) {
        int b = (tid >> 4) * 2, ii = tid & 15;
        float s = red[b * 16 + ii] + red[(b + 1) * 16 + ii] + b_do[0];
        dp[tid] = fsigmoid(s);
    }
    __syncthreads();

    // ---- head layer 1: feats(387) -> 256 ----
    {
        float b0 = b_f1[j0], b1 = b_f1[j0 + 128];
        #pragma unroll
        for (int e = 0; e < 16; ++e) { acc0[e] = b0; acc1[e] = b1; }
        mm256seg(nsrc32, 64, W_f1);                    // rows 0..127  : node_emb[src]
        mm256seg(ndst32, 64, W_f1 + 128 * 256);        // rows 128..255: node_emb[dst]
        mm256seg(bufA32, 64, W_f1 + 256 * 256);        // rows 256..383: e3
        float t0a = W_f1[384 * 256 + j0], t0b = W_f1[384 * 256 + 128 + j0];
        float t1a = W_f1[385 * 256 + j0], t1b = W_f1[385 * 256 + 128 + j0];
        float t2a = W_f1[386 * 256 + j0], t2b = W_f1[386 * 256 + 128 + j0];
        #pragma unroll
        for (int e = 0; e < 16; ++e) {
            int ge = ebase + e;
            float dpe = dp[ge], pse = ps[ge], pde = pd[ge];
            acc0[e] = fmaf(dpe, t0a, fmaf(pse, t1a, fmaf(pde, t2a, acc0[e])));
            acc1[e] = fmaf(dpe, t0b, fmaf(pse, t1b, fmaf(pde, t2b, acc1[e])));
        }
        #pragma unroll
        for (int e = 0; e < 16; ++e) {                 // x1 overwrites hd1 region
            int ge = ebase + e;
            hd1[ge * 256 + j0]       = f2bf(fsilu(acc0[e]));
            hd1[ge * 256 + 128 + j0] = f2bf(fsilu(acc1[e]));
        }
    }
    __syncthreads();

    // ---- head layer 2 (256 -> 256) fused with W_bo dot ----
    {
        float b0 = b_f2[j0], b1 = b_f2[j0 + 128];
        #pragma unroll
        for (int e = 0; e < 16; ++e) { acc0[e] = b0; acc1[e] = b1; }
        mm256seg(hd132, 128, W_f2);
        float w0 = W_bo[j0], w1 = W_bo[j0 + 128];
        float part[16];
        #pragma unroll
        for (int e = 0; e < 16; ++e)
            part[e] = fsilu(acc0[e]) * w0 + fsilu(acc1[e]) * w1;
        #pragma unroll
        for (int off = 32; off; off >>= 1) {
            #pragma unroll
            for (int e = 0; e < 16; ++e) part[e] += __shfl_xor(part[e], off);
        }
        if (lane == 0) {
            #pragma unroll
            for (int e = 0; e < 16; ++e) red[wid * 16 + e] = part[e];
        }
    }
    __syncthreads();
    if (tid < 32) {
        int ge = e0 + tid;
        if (ge < E) {
            int b = (tid >> 4) * 2, ii = tid & 15;
            out[ge] = red[b * 16 + ii] + red[(b + 1) * 16 + ii] + b_bo[0];
        }
    }
}

extern "C" void kernel_launch(void* const* d_in, const int* in_sizes, int n_in,
                              void* d_out, int out_size, void* d_ws, size_t ws_size,
                              hipStream_t stream) {
    const float* node_emb   = (const float*)d_in[0];
    const int*   edge_index = (const int*)d_in[1];
    const float* edge_attr  = (const float*)d_in[2];
    const float* dual_emb   = (const float*)d_in[3];
    const float* logits     = (const float*)d_in[4];
    const float* W_be1 = (const float*)d_in[5];
    const float* b_be1 = (const float*)d_in[6];
    const float* g_be1 = (const float*)d_in[7];
    const float* bb_be1= (const float*)d_in[8];
    const float* W_be2 = (const float*)d_in[9];
    const float* b_be2 = (const float*)d_in[10];
    const float* g_be2 = (const float*)d_in[11];
    const float* bb_be2= (const float*)d_in[12];
    const float* W_be3 = (const float*)d_in[13];
    const float* b_be3 = (const float*)d_in[14];
    const float* g_be3 = (const float*)d_in[15];
    const float* bb_be3= (const float*)d_in[16];
    const float* W_d1  = (const float*)d_in[17];
    const float* b_d1  = (const float*)d_in[18];
    const float* W_d2  = (const float*)d_in[19];
    const float* b_d2  = (const float*)d_in[20];
    const float* W_do  = (const float*)d_in[21];
    const float* b_do  = (const float*)d_in[22];
    const float* W_f1  = (const float*)d_in[23];
    const float* b_f1  = (const float*)d_in[24];
    const float* W_f2  = (const float*)d_in[25];
    const float* b_f2  = (const float*)d_in[26];
    const float* W_bo  = (const float*)d_in[27];
    const float* b_bo  = (const float*)d_in[28];
    float* out = (float*)d_out;

    int E = in_sizes[2] / 16;
    int nblocks = (E + TILE - 1) / TILE;
    bondpred_kernel<<<dim3(nblocks), dim3(256), 0, stream>>>(
        node_emb, edge_index, edge_attr, dual_emb, logits,
        W_be1, b_be1, g_be1, bb_be1,
        W_be2, b_be2, g_be2, bb_be2,
        W_be3, b_be3, g_be3, bb_be3,
        W_d1, b_d1, W_d2, b_d2, W_do, b_do,
        W_f1, b_f1, W_f2, b_f2, W_bo, b_bo,
        out, E);
}

// Round 3
// 1568.126 us; speedup vs baseline: 2.5297x; 2.5297x over previous
//
#include <hip/hip_runtime.h>
#include <stdint.h>

typedef __attribute__((ext_vector_type(8))) short bf16x8;
typedef __attribute__((ext_vector_type(4))) float f32x4;
typedef __attribute__((ext_vector_type(4))) float float4v;

__device__ __forceinline__ uint16_t f2bf(float f){
    union{float f;uint32_t u;}v; v.f = f;
    return (uint16_t)((v.u + 0x7fffu + ((v.u >> 16) & 1u)) >> 16);  // RNE
}
__device__ __forceinline__ float fsigmoid(float x){ return 1.0f / (1.0f + __expf(-x)); }
__device__ __forceinline__ float fsilu(float x){ return x * fsigmoid(x); }

__device__ __forceinline__ bf16x8 pack8(float4v lo, float4v hi){
    bf16x8 r;
    r[0]=(short)f2bf(lo[0]); r[1]=(short)f2bf(lo[1]);
    r[2]=(short)f2bf(lo[2]); r[3]=(short)f2bf(lo[3]);
    r[4]=(short)f2bf(hi[0]); r[5]=(short)f2bf(hi[1]);
    r[6]=(short)f2bf(hi[2]); r[7]=(short)f2bf(hi[3]);
    return r;
}

// LDS layout (134144 B total, 1 block/CU):
//   [0      .. 32768)  bufE  : 4 waves x bf16[32][128] (XOR-swizzled), bond-emb act
//   [32768  .. 98304)  h256  : 4 waves x bf16[32][256] (XOR-swizzled), 256-wide act
//   [98304  .. 131072) wbuf  : 2 x 16KB weight-fragment chunk (double buffer)
//   [131072 ..134144)  misc  : 4 waves x 768B {ps,pd,dp,sidx,didx}
#define LDS_TOTAL 134144

__global__ void __launch_bounds__(256, 1)
bond_fused_kernel(const float* __restrict__ node_emb, const int* __restrict__ edge_index,
                  const float* __restrict__ edge_attr, const float* __restrict__ dual_emb,
                  const float* __restrict__ logits,
                  const float* __restrict__ W_be1, const float* __restrict__ b_be1,
                  const float* __restrict__ g_be1, const float* __restrict__ bb_be1,
                  const float* __restrict__ W_be2, const float* __restrict__ b_be2,
                  const float* __restrict__ g_be2, const float* __restrict__ bb_be2,
                  const float* __restrict__ W_be3, const float* __restrict__ b_be3,
                  const float* __restrict__ g_be3, const float* __restrict__ bb_be3,
                  const float* __restrict__ W_d1, const float* __restrict__ b_d1,
                  const float* __restrict__ W_d2, const float* __restrict__ b_d2,
                  const float* __restrict__ W_do, const float* __restrict__ b_do,
                  const float* __restrict__ W_f1, const float* __restrict__ b_f1,
                  const float* __restrict__ W_f2, const float* __restrict__ b_f2,
                  const float* __restrict__ W_bo, const float* __restrict__ b_bo,
                  float* __restrict__ out, int E)
{
    __shared__ char lds[LDS_TOTAL];
    const int t    = threadIdx.x;
    const int wave = t >> 6;
    const int lane = t & 63;
    const int li   = lane & 15, lg = lane >> 4;
    const int e0   = blockIdx.x * 128 + wave * 32;

    char* bufE = lds + wave * 8192;
    char* h256 = lds + 32768 + wave * 16384;
    uint16_t* wb0 = (uint16_t*)(lds + 98304);
    uint16_t* wb1 = (uint16_t*)(lds + 114688);
    float* ps  = (float*)(lds + 131072 + wave * 768);
    float* pd  = ps + 32;
    float* dpv = ps + 64;
    int* sidx  = (int*)(ps + 96);
    int* didx  = sidx + 32;

    // ---- per-wave gather: indices + atom sigmoids (before first barrier) ----
    if (lane < 32) {
        int e = e0 + lane; if (e >= E) e = E - 1;
        int s_ = edge_index[e];
        int d_ = edge_index[E + e];
        sidx[lane] = s_; didx[lane] = d_;
        ps[lane] = fsigmoid(logits[s_]);
        pd[lane] = fsigmoid(logits[d_]);
    }

    // ================= weight-streaming machinery =================
    // frag layout per (kt-group): elem = ct*512 + ln*8 + (k&7), ln = ((k&31)>>3)*16 + (c&15)
    // -> lane l reads 16B at l*8: col c = (l&15)+16*ct, k-slots (l>>4)*8 + j. Same k-map as A packs.
    float4v sr[8];
    auto issueW = [&](const float* W, int OUT, int kbase, int K){
        if (OUT == 128){
            int dk = t >> 5, dc = t & 31;
            int k0 = kbase + dk * 4, c0 = dc * 4;
            #pragma unroll
            for (int i = 0; i < 4; ++i){
                float4v z = {0.f, 0.f, 0.f, 0.f};
                sr[i] = (k0 + i < K) ? *(const float4v*)(W + (size_t)(k0 + i) * 128 + c0) : z;
            }
        } else {
            #pragma unroll
            for (int h = 0; h < 2; ++h){
                int id = t + h * 256;
                int dk = id >> 6, dc = id & 63;
                int k0 = kbase + dk * 4, c0 = dc * 4;
                #pragma unroll
                for (int i = 0; i < 4; ++i)
                    sr[h * 4 + i] = *(const float4v*)(W + (size_t)(k0 + i) * 256 + c0);
            }
        }
    };
    auto commitW = [&](uint16_t* dst, int OUT){
        if (OUT == 128){
            int dk = t >> 5, dc = t & 31;
            int k0 = dk * 4, c0 = dc * 4;
            #pragma unroll
            for (int cc = 0; cc < 4; ++cc){
                int c = c0 + cc, fid = c >> 4;
                int ln = ((k0 & 31) >> 3) * 16 + (c & 15);
                uint2 wv;
                wv.x = (uint32_t)f2bf(sr[0][cc]) | ((uint32_t)f2bf(sr[1][cc]) << 16);
                wv.y = (uint32_t)f2bf(sr[2][cc]) | ((uint32_t)f2bf(sr[3][cc]) << 16);
                *(uint2*)(dst + fid * 512 + ln * 8 + (k0 & 7)) = wv;
            }
        } else {
            #pragma unroll
            for (int h = 0; h < 2; ++h){
                int id = t + h * 256;
                int dk = id >> 6, dc = id & 63;
                int k0 = dk * 4, c0 = dc * 4;
                #pragma unroll
                for (int cc = 0; cc < 4; ++cc){
                    int c = c0 + cc, fid = c >> 4;
                    int ln = ((k0 & 31) >> 3) * 16 + (c & 15);
                    uint2 wv;
                    wv.x = (uint32_t)f2bf(sr[h*4+0][cc]) | ((uint32_t)f2bf(sr[h*4+1][cc]) << 16);
                    wv.y = (uint32_t)f2bf(sr[h*4+2][cc]) | ((uint32_t)f2bf(sr[h*4+3][cc]) << 16);
                    *(uint2*)(dst + fid * 512 + ln * 8 + (k0 & 7)) = wv;
                }
            }
        }
    };

    int cur = 0;
    auto stepend = [&](int OUTnext){
        if (OUTnext) commitW(cur ? wb0 : wb1, OUTnext);
        __syncthreads();
        cur ^= 1;
    };
    auto curbuf = [&]() -> const uint16_t* { return cur ? wb1 : wb0; };

    // ================= compute machinery (per wave, 32 edges) =================
    f32x4 acc[2][16];   // C: col = li+16*ct, row = rt*16 + lg*4 + r

    auto ldf = [&](const uint16_t* w, int fid) -> bf16x8 {
        return *(const bf16x8*)(w + fid * 512 + lane * 8);
    };
    auto grp128 = [&](const uint16_t* w, bf16x8 a0, bf16x8 a1){
        #pragma unroll
        for (int ct = 0; ct < 8; ++ct){
            bf16x8 b = ldf(w, ct);
            acc[0][ct] = __builtin_amdgcn_mfma_f32_16x16x32_bf16(a0, b, acc[0][ct], 0, 0, 0);
            acc[1][ct] = __builtin_amdgcn_mfma_f32_16x16x32_bf16(a1, b, acc[1][ct], 0, 0, 0);
        }
    };
    auto grp256 = [&](const uint16_t* w, bf16x8 a0, bf16x8 a1){
        #pragma unroll
        for (int ct = 0; ct < 16; ++ct){
            bf16x8 b = ldf(w, ct);
            acc[0][ct] = __builtin_amdgcn_mfma_f32_16x16x32_bf16(a0, b, acc[0][ct], 0, 0, 0);
            acc[1][ct] = __builtin_amdgcn_mfma_f32_16x16x32_bf16(a1, b, acc[1][ct], 0, 0, 0);
        }
    };
    auto init128 = [&](const float* b){
        #pragma unroll
        for (int ct = 0; ct < 8; ++ct){
            float bv = b[li + 16 * ct];
            f32x4 iv = {bv, bv, bv, bv};
            acc[0][ct] = iv; acc[1][ct] = iv;
        }
    };
    auto init256 = [&](const float* b){
        #pragma unroll
        for (int ct = 0; ct < 16; ++ct){
            float bv = b[li + 16 * ct];
            f32x4 iv = {bv, bv, bv, bv};
            acc[0][ct] = iv; acc[1][ct] = iv;
        }
    };
    // bufE / h256 accessors (XOR swizzle on byte offset)
    auto eb_read8 = [&](int row, int kt) -> bf16x8 {
        int off = row * 256 + (kt * 32 + lg * 8) * 2;
        return *(const bf16x8*)(bufE + (off ^ ((row & 7) << 4)));
    };
    auto h2_read8 = [&](int row, int kt) -> bf16x8 {
        int off = row * 512 + (kt * 32 + lg * 8) * 2;
        return *(const bf16x8*)(h256 + (off ^ ((row & 7) << 4)));
    };
    auto lnstore = [&](const float* g, const float* bb){
        float gv[8], bv[8];
        #pragma unroll
        for (int ct = 0; ct < 8; ++ct){ gv[ct] = g[li + 16*ct]; bv[ct] = bb[li + 16*ct]; }
        #pragma unroll
        for (int rt = 0; rt < 2; ++rt){
            #pragma unroll
            for (int r = 0; r < 4; ++r){
                float s = 0.f, q = 0.f;
                #pragma unroll
                for (int ct = 0; ct < 8; ++ct){ float v = acc[rt][ct][r]; s += v; q += v*v; }
                s += __shfl_xor(s, 1); q += __shfl_xor(q, 1);
                s += __shfl_xor(s, 2); q += __shfl_xor(q, 2);
                s += __shfl_xor(s, 4); q += __shfl_xor(q, 4);
                s += __shfl_xor(s, 8); q += __shfl_xor(q, 8);
                float mu = s * 0.0078125f;
                float var = q * 0.0078125f - mu * mu;
                float rs = rsqrtf(var + 1e-5f);
                int row = rt * 16 + lg * 4 + r;
                int rswz = (row & 7) << 4;
                #pragma unroll
                for (int ct = 0; ct < 8; ++ct){
                    float v = (acc[rt][ct][r] - mu) * rs * gv[ct] + bv[ct];
                    int off = row * 256 + (li + 16 * ct) * 2;
                    *(uint16_t*)(bufE + (off ^ rswz)) = f2bf(fsilu(v));
                }
            }
        }
    };
    auto silustore256 = [&](){
        #pragma unroll
        for (int rt = 0; rt < 2; ++rt){
            #pragma unroll
            for (int r = 0; r < 4; ++r){
                int row = rt * 16 + lg * 4 + r;
                int rswz = (row & 7) << 4;
                #pragma unroll
                for (int ct = 0; ct < 16; ++ct){
                    int off = row * 512 + (li + 16 * ct) * 2;
                    *(uint16_t*)(h256 + (off ^ rswz)) = f2bf(fsilu(acc[rt][ct][r]));
                }
            }
        }
    };

    // ================= prologue: stage group 0 (BE1) =================
    issueW(W_be1, 128, 0, 16);
    commitW(wb0, 128);
    __syncthreads();

    // ---- g0: BE1 (K=16 zero-padded to 32) ----
    issueW(W_be2, 128, 0, 128);
    {
        init128(b_be1);
        bf16x8 aE[2];
        #pragma unroll
        for (int rt = 0; rt < 2; ++rt){
            bf16x8 z = {0,0,0,0,0,0,0,0};
            if (lg < 2){
                int e = e0 + rt * 16 + li; if (e >= E) e = E - 1;
                const float* p = edge_attr + (size_t)e * 16 + lg * 8;
                z = pack8(*(const float4v*)p, *(const float4v*)(p + 4));
            }
            aE[rt] = z;
        }
        grp128(curbuf(), aE[0], aE[1]);
        lnstore(g_be1, bb_be1);
    }
    stepend(128);

    // ---- g1..4: BE2 ----
    {
        bf16x8 A0[4], A1[4];
        #pragma unroll
        for (int kt = 0; kt < 4; ++kt){
            if (kt < 3) issueW(W_be2, 128, (kt + 1) * 32, 128);
            else        issueW(W_be3, 128, 0, 128);
            if (kt == 0){
                init128(b_be2);
                #pragma unroll
                for (int k2 = 0; k2 < 4; ++k2){ A0[k2] = eb_read8(li, k2); A1[k2] = eb_read8(16 + li, k2); }
            }
            grp128(curbuf(), A0[kt], A1[kt]);
            if (kt == 3) lnstore(g_be2, bb_be2);
            stepend(128);
        }
    }
    // ---- g5..8: BE3 ----
    {
        bf16x8 A0[4], A1[4];
        #pragma unroll
        for (int kt = 0; kt < 4; ++kt){
            if (kt < 3) issueW(W_be3, 128, (kt + 1) * 32, 128);
            else        issueW(W_d1, 256, 0, 128);
            if (kt == 0){
                init128(b_be3);
                #pragma unroll
                for (int k2 = 0; k2 < 4; ++k2){ A0[k2] = eb_read8(li, k2); A1[k2] = eb_read8(16 + li, k2); }
            }
            grp128(curbuf(), A0[kt], A1[kt]);
            if (kt == 3) lnstore(g_be3, bb_be3);      // e3 stays in bufE
            stepend(kt < 3 ? 128 : 256);
        }
    }

    // ---- g9..12: D1 (128 -> 256), A from dual_emb (1-deep prefetch) ----
    {
        float4v cA[4], nA[4];
        {
            int ea = e0 + li;      if (ea >= E) ea = E - 1;
            int eb = e0 + 16 + li; if (eb >= E) eb = E - 1;
            const float* pa = dual_emb + (size_t)ea * 128 + lg * 8;
            const float* pb = dual_emb + (size_t)eb * 128 + lg * 8;
            cA[0] = *(const float4v*)pa; cA[1] = *(const float4v*)(pa + 4);
            cA[2] = *(const float4v*)pb; cA[3] = *(const float4v*)(pb + 4);
        }
        #pragma unroll
        for (int kt = 0; kt < 4; ++kt){
            if (kt < 3) issueW(W_d1, 256, (kt + 1) * 32, 128);
            else        issueW(W_d2, 256, 0, 256);
            if (kt < 3){
                int ea = e0 + li;      if (ea >= E) ea = E - 1;
                int eb = e0 + 16 + li; if (eb >= E) eb = E - 1;
                const float* pa = dual_emb + (size_t)ea * 128 + (kt + 1) * 32 + lg * 8;
                const float* pb = dual_emb + (size_t)eb * 128 + (kt + 1) * 32 + lg * 8;
                nA[0] = *(const float4v*)pa; nA[1] = *(const float4v*)(pa + 4);
                nA[2] = *(const float4v*)pb; nA[3] = *(const float4v*)(pb + 4);
            }
            if (kt == 0) init256(b_d1);
            grp256(curbuf(), pack8(cA[0], cA[1]), pack8(cA[2], cA[3]));
            if (kt < 3){ cA[0]=nA[0]; cA[1]=nA[1]; cA[2]=nA[2]; cA[3]=nA[3]; }
            if (kt == 3) silustore256();
            stepend(256);
        }
    }

    // ---- g13..20: D2 (256 -> 256) + fused W_do dot ----
    {
        #pragma unroll
        for (int kt = 0; kt < 8; ++kt){
            if (kt < 7) issueW(W_d2, 256, (kt + 1) * 32, 256);
            else        issueW(W_f1, 256, 0, 384);
            if (kt == 0) init256(b_d2);
            grp256(curbuf(), h2_read8(li, kt), h2_read8(16 + li, kt));
            if (kt == 7){
                float wdo[16];
                #pragma unroll
                for (int ct = 0; ct < 16; ++ct) wdo[ct] = W_do[li + 16 * ct];
                float bdo0 = b_do[0];
                #pragma unroll
                for (int rt = 0; rt < 2; ++rt){
                    #pragma unroll
                    for (int r = 0; r < 4; ++r){
                        float s = 0.f;
                        #pragma unroll
                        for (int ct = 0; ct < 16; ++ct) s += fsilu(acc[rt][ct][r]) * wdo[ct];
                        s += __shfl_xor(s, 1); s += __shfl_xor(s, 2);
                        s += __shfl_xor(s, 4); s += __shfl_xor(s, 8);
                        if (li == 0) dpv[rt * 16 + lg * 4 + r] = fsigmoid(s + bdo0);
                    }
                }
            }
            stepend(256);
        }
    }

    // ---- g21..32: F1 (387 -> 256) ----
    {
        int s0 = sidx[li], s1 = sidx[16 + li];
        int d0 = didx[li], d1 = didx[16 + li];
        float4v cA[4], nA[4];
        {
            const float* pa = node_emb + (size_t)s0 * 128 + lg * 8;
            const float* pb = node_emb + (size_t)s1 * 128 + lg * 8;
            cA[0] = *(const float4v*)pa; cA[1] = *(const float4v*)(pa + 4);
            cA[2] = *(const float4v*)pb; cA[3] = *(const float4v*)(pb + 4);
        }
        #pragma unroll
        for (int kt = 0; kt < 12; ++kt){
            if (kt < 11) issueW(W_f1, 256, (kt + 1) * 32, 384);
            else         issueW(W_f2, 256, 0, 256);
            // prefetch next A (node rows) for kt+1 in [1,8)
            if (kt < 7){
                int nk = kt + 1;
                int ra = (nk < 4) ? s0 : d0;
                int rb = (nk < 4) ? s1 : d1;
                int ko = (nk & 3) * 32 + lg * 8;
                const float* pa = node_emb + (size_t)ra * 128 + ko;
                const float* pb = node_emb + (size_t)rb * 128 + ko;
                nA[0] = *(const float4v*)pa; nA[1] = *(const float4v*)(pa + 4);
                nA[2] = *(const float4v*)pb; nA[3] = *(const float4v*)(pb + 4);
            }
            if (kt == 0){
                float dpr[2][4], psr[2][4], pdr[2][4];
                #pragma unroll
                for (int rt = 0; rt < 2; ++rt)
                    #pragma unroll
                    for (int r = 0; r < 4; ++r){
                        int row = rt * 16 + lg * 4 + r;
                        dpr[rt][r] = dpv[row]; psr[rt][r] = ps[row]; pdr[rt][r] = pd[row];
                    }
                #pragma unroll
                for (int ct = 0; ct < 16; ++ct){
                    int col = li + 16 * ct;
                    float bv = b_f1[col];
                    float t0 = W_f1[384 * 256 + col];
                    float t1 = W_f1[385 * 256 + col];
                    float t2 = W_f1[386 * 256 + col];
                    #pragma unroll
                    for (int rt = 0; rt < 2; ++rt)
                        #pragma unroll
                        for (int r = 0; r < 4; ++r)
                            acc[rt][ct][r] = bv + dpr[rt][r]*t0 + psr[rt][r]*t1 + pdr[rt][r]*t2;
                }
            }
            bf16x8 a0, a1;
            if (kt < 8){ a0 = pack8(cA[0], cA[1]); a1 = pack8(cA[2], cA[3]); }
            else       { a0 = eb_read8(li, kt - 8); a1 = eb_read8(16 + li, kt - 8); }
            grp256(curbuf(), a0, a1);
            if (kt < 7){ cA[0]=nA[0]; cA[1]=nA[1]; cA[2]=nA[2]; cA[3]=nA[3]; }
            if (kt == 11) silustore256();
            stepend(256);
        }
    }

    // ---- g33..40: F2 (256 -> 256) + fused W_bo dot -> out ----
    {
        #pragma unroll
        for (int kt = 0; kt < 8; ++kt){
            if (kt < 7) issueW(W_f2, 256, (kt + 1) * 32, 256);
            if (kt == 0) init256(b_f2);
            grp256(curbuf(), h2_read8(li, kt), h2_read8(16 + li, kt));
            if (kt == 7){
                float wbo[16];
                #pragma unroll
                for (int ct = 0; ct < 16; ++ct) wbo[ct] = W_bo[li + 16 * ct];
                float bbo0 = b_bo[0];
                #pragma unroll
                for (int rt = 0; rt < 2; ++rt){
                    #pragma unroll
                    for (int r = 0; r < 4; ++r){
                        float s = 0.f;
                        #pragma unroll
                        for (int ct = 0; ct < 16; ++ct) s += fsilu(acc[rt][ct][r]) * wbo[ct];
                        s += __shfl_xor(s, 1); s += __shfl_xor(s, 2);
                        s += __shfl_xor(s, 4); s += __shfl_xor(s, 8);
                        if (li == 0){
                            int e = e0 + rt * 16 + lg * 4 + r;
                            if (e < E) out[e] = s + bbo0;
                        }
                    }
                }
            }
            stepend(kt < 7 ? 256 : 0);
        }
    }
}

extern "C" void kernel_launch(void* const* d_in, const int* in_sizes, int n_in,
                              void* d_out, int out_size, void* d_ws, size_t ws_size,
                              hipStream_t stream) {
    const float* node_emb   = (const float*)d_in[0];
    const int*   edge_index = (const int*)d_in[1];
    const float* edge_attr  = (const float*)d_in[2];
    const float* dual_emb   = (const float*)d_in[3];
    const float* logits     = (const float*)d_in[4];
    const float* W_be1 = (const float*)d_in[5];
    const float* b_be1 = (const float*)d_in[6];
    const float* g_be1 = (const float*)d_in[7];
    const float* bb_be1= (const float*)d_in[8];
    const float* W_be2 = (const float*)d_in[9];
    const float* b_be2 = (const float*)d_in[10];
    const float* g_be2 = (const float*)d_in[11];
    const float* bb_be2= (const float*)d_in[12];
    const float* W_be3 = (const float*)d_in[13];
    const float* b_be3 = (const float*)d_in[14];
    const float* g_be3 = (const float*)d_in[15];
    const float* bb_be3= (const float*)d_in[16];
    const float* W_d1  = (const float*)d_in[17];
    const float* b_d1  = (const float*)d_in[18];
    const float* W_d2  = (const float*)d_in[19];
    const float* b_d2  = (const float*)d_in[20];
    const float* W_do  = (const float*)d_in[21];
    const float* b_do  = (const float*)d_in[22];
    const float* W_f1  = (const float*)d_in[23];
    const float* b_f1  = (const float*)d_in[24];
    const float* W_f2  = (const float*)d_in[25];
    const float* b_f2  = (const float*)d_in[26];
    const float* W_bo  = (const float*)d_in[27];
    const float* b_bo  = (const float*)d_in[28];
    float* out = (float*)d_out;

    int E = in_sizes[2] / 16;
    int nblocks = (E + 127) / 128;
    bond_fused_kernel<<<dim3(nblocks), dim3(256), 0, stream>>>(
        node_emb, edge_index, edge_attr, dual_emb, logits,
        W_be1, b_be1, g_be1, bb_be1,
        W_be2, b_be2, g_be2, bb_be2,
        W_be3, b_be3, g_be3, bb_be3,
        W_d1, b_d1, W_d2, b_d2, W_do, b_do,
        W_f1, b_f1, W_f2, b_f2, W_bo, b_bo,
        out, E);
}

// Round 4
// 1532.952 us; speedup vs baseline: 2.5878x; 1.0229x over previous
//
#include <hip/hip_runtime.h>
#include <hip/hip_bf16.h>
#include <stdint.h>

typedef __attribute__((ext_vector_type(8))) short bf16x8;
typedef __attribute__((ext_vector_type(4))) float f32x4;
typedef __attribute__((ext_vector_type(4))) float float4v;

__device__ __forceinline__ uint16_t bfc(float x){
    __hip_bfloat16 h = __float2bfloat16(x);          // RNE, compiler cvt path
    return __builtin_bit_cast(uint16_t, h);
}
__device__ __forceinline__ uint32_t pk2(float a, float b){
    return (uint32_t)bfc(a) | ((uint32_t)bfc(b) << 16);
}
__device__ __forceinline__ float fsigmoid(float x){ return 1.0f / (1.0f + __expf(-x)); }
__device__ __forceinline__ float fsilu(float x){ return x * fsigmoid(x); }

__device__ __forceinline__ bf16x8 pack8(float4v lo, float4v hi){
    bf16x8 r;
    r[0]=(short)bfc(lo[0]); r[1]=(short)bfc(lo[1]);
    r[2]=(short)bfc(lo[2]); r[3]=(short)bfc(lo[3]);
    r[4]=(short)bfc(hi[0]); r[5]=(short)bfc(hi[1]);
    r[6]=(short)bfc(hi[2]); r[7]=(short)bfc(hi[3]);
    return r;
}

// LDS layout (134144 B, 1 block/CU):
//   [0      .. 32768)  bufE : 4 waves x bf16[32][128] (XOR swizzle), 128-wide act
//   [32768  .. 98304)  h256 : 4 waves x bf16[32][256] (XOR swizzle), 256-wide act
//   [98304  .. 131072) wbuf : 2 x 16KB weight-fragment chunk (double buffer)
//   [131072 ..134144)  misc : 4 waves x 768B {ps,pd,dp,sidx,didx}
#define LDS_TOTAL 134144

__global__ void __launch_bounds__(256, 1)
bond_fused_kernel(const float* __restrict__ node_emb, const int* __restrict__ edge_index,
                  const float* __restrict__ edge_attr, const float* __restrict__ dual_emb,
                  const float* __restrict__ logits,
                  const float* __restrict__ W_be1, const float* __restrict__ b_be1,
                  const float* __restrict__ g_be1, const float* __restrict__ bb_be1,
                  const float* __restrict__ W_be2, const float* __restrict__ b_be2,
                  const float* __restrict__ g_be2, const float* __restrict__ bb_be2,
                  const float* __restrict__ W_be3, const float* __restrict__ b_be3,
                  const float* __restrict__ g_be3, const float* __restrict__ bb_be3,
                  const float* __restrict__ W_d1, const float* __restrict__ b_d1,
                  const float* __restrict__ W_d2, const float* __restrict__ b_d2,
                  const float* __restrict__ W_do, const float* __restrict__ b_do,
                  const float* __restrict__ W_f1, const float* __restrict__ b_f1,
                  const float* __restrict__ W_f2, const float* __restrict__ b_f2,
                  const float* __restrict__ W_bo, const float* __restrict__ b_bo,
                  float* __restrict__ out, int E)
{
    __shared__ char lds[LDS_TOTAL];
    const int t    = threadIdx.x;
    const int wave = t >> 6;
    const int lane = t & 63;
    const int li   = lane & 15, lg = lane >> 4;
    const int e0   = blockIdx.x * 128 + wave * 32;

    char* bufE = lds + wave * 8192;
    char* h256 = lds + 32768 + wave * 16384;
    uint16_t* wb0 = (uint16_t*)(lds + 98304);
    uint16_t* wb1 = (uint16_t*)(lds + 114688);
    float* ps  = (float*)(lds + 131072 + wave * 768);
    float* pd  = ps + 32;
    float* dpv = ps + 64;
    int* sidx  = (int*)(ps + 96);
    int* didx  = sidx + 32;

    // ---- per-wave gather: indices + atom sigmoids ----
    if (lane < 32) {
        int e = e0 + lane; if (e >= E) e = E - 1;
        int s_ = edge_index[e];
        int d_ = edge_index[E + e];
        sidx[lane] = s_; didx[lane] = d_;
        ps[lane] = fsigmoid(logits[s_]);
        pd[lane] = fsigmoid(logits[d_]);
    }

    // ================= weight staging: linear frag commit =================
    // frag elem e = fid*512 + ln*8 + j  <->  B[k0 + (ln>>4)*8 + j][fid*16 + (ln&15)]
    // thread t stages ln = lane, fid = wave + 4h  ->  b128 writes are wave-linear
    // (conflict-free); loads are 64B-run coalesced.
    float sr[4][8];
    auto issueW256 = [&](const float* W, int kbase){
        #pragma unroll
        for (int h = 0; h < 4; ++h){
            const float* p = W + (size_t)(kbase + lg * 8) * 256 + (wave + 4*h) * 16 + li;
            #pragma unroll
            for (int j = 0; j < 8; ++j) sr[h][j] = p[j * 256];
        }
    };
    auto issueW128 = [&](const float* W, int kbase, int K){
        #pragma unroll
        for (int h = 0; h < 2; ++h){
            const float* p = W + (size_t)(kbase + lg * 8) * 128 + (wave + 4*h) * 16 + li;
            #pragma unroll
            for (int j = 0; j < 8; ++j)
                sr[h][j] = (kbase + lg * 8 + j < K) ? p[j * 128] : 0.f;
        }
    };
    auto commitW = [&](uint16_t* dst, int nh){
        #pragma unroll
        for (int h = 0; h < 4; ++h){
            if (h < nh){
                uint4 w;
                w.x = pk2(sr[h][0], sr[h][1]); w.y = pk2(sr[h][2], sr[h][3]);
                w.z = pk2(sr[h][4], sr[h][5]); w.w = pk2(sr[h][6], sr[h][7]);
                *(uint4*)(dst + (wave + 4*h) * 512 + lane * 8) = w;
            }
        }
    };

    int cur = 0;
    auto stepend = [&](int mode){
        if (mode) commitW(cur ? wb0 : wb1, mode == 128 ? 2 : 4);
        __syncthreads();
        cur ^= 1;
    };
    auto curbuf = [&]() -> const uint16_t* { return cur ? wb1 : wb0; };

    // ================= compute machinery (per wave, 32 edges) =================
    f32x4 acc[2][16];   // C: col = li+16*ct, row = rt*16 + lg*4 + r

    auto ldf = [&](const uint16_t* w, int fid) -> bf16x8 {
        return *(const bf16x8*)(w + fid * 512 + lane * 8);
    };
    auto grp128 = [&](const uint16_t* w, bf16x8 a0, bf16x8 a1){
        #pragma unroll
        for (int ct = 0; ct < 8; ++ct){
            bf16x8 b = ldf(w, ct);
            acc[0][ct] = __builtin_amdgcn_mfma_f32_16x16x32_bf16(a0, b, acc[0][ct], 0, 0, 0);
            acc[1][ct] = __builtin_amdgcn_mfma_f32_16x16x32_bf16(a1, b, acc[1][ct], 0, 0, 0);
        }
    };
    auto grp256 = [&](const uint16_t* w, bf16x8 a0, bf16x8 a1){
        #pragma unroll
        for (int ct = 0; ct < 16; ++ct){
            bf16x8 b = ldf(w, ct);
            acc[0][ct] = __builtin_amdgcn_mfma_f32_16x16x32_bf16(a0, b, acc[0][ct], 0, 0, 0);
            acc[1][ct] = __builtin_amdgcn_mfma_f32_16x16x32_bf16(a1, b, acc[1][ct], 0, 0, 0);
        }
    };
    auto init128 = [&](const float* b){
        #pragma unroll
        for (int ct = 0; ct < 8; ++ct){
            float bv = b[li + 16 * ct];
            f32x4 iv = {bv, bv, bv, bv};
            acc[0][ct] = iv; acc[1][ct] = iv;
        }
    };
    auto init256 = [&](const float* b){
        #pragma unroll
        for (int ct = 0; ct < 16; ++ct){
            float bv = b[li + 16 * ct];
            f32x4 iv = {bv, bv, bv, bv};
            acc[0][ct] = iv; acc[1][ct] = iv;
        }
    };
    auto eb_read8 = [&](int row, int kt) -> bf16x8 {
        int off = row * 256 + (kt * 32 + lg * 8) * 2;
        return *(const bf16x8*)(bufE + (off ^ ((row & 7) << 4)));
    };
    auto h2_read8 = [&](int row, int kt) -> bf16x8 {
        int off = row * 512 + (kt * 32 + lg * 8) * 2;
        return *(const bf16x8*)(h256 + (off ^ ((row & 7) << 4)));
    };
    auto lnstore = [&](const float* g, const float* bb){
        #pragma unroll
        for (int rt = 0; rt < 2; ++rt){
            #pragma unroll
            for (int r = 0; r < 4; ++r){
                float s = 0.f, q = 0.f;
                #pragma unroll
                for (int ct = 0; ct < 8; ++ct){ float v = acc[rt][ct][r]; s += v; q += v*v; }
                s += __shfl_xor(s, 1); q += __shfl_xor(q, 1);
                s += __shfl_xor(s, 2); q += __shfl_xor(q, 2);
                s += __shfl_xor(s, 4); q += __shfl_xor(q, 4);
                s += __shfl_xor(s, 8); q += __shfl_xor(q, 8);
                float mu = s * 0.0078125f;
                float var = q * 0.0078125f - mu * mu;
                float rs = rsqrtf(var + 1e-5f);
                int row = rt * 16 + lg * 4 + r;
                int rswz = (row & 7) << 4;
                #pragma unroll
                for (int ct = 0; ct < 8; ++ct){
                    int col = li + 16 * ct;
                    float v = (acc[rt][ct][r] - mu) * rs * g[col] + bb[col];
                    int off = row * 256 + col * 2;
                    *(uint16_t*)(bufE + (off ^ rswz)) = bfc(fsilu(v));
                }
            }
        }
    };
    auto silustore256 = [&](){
        #pragma unroll
        for (int rt = 0; rt < 2; ++rt){
            #pragma unroll
            for (int r = 0; r < 4; ++r){
                int row = rt * 16 + lg * 4 + r;
                int rswz = (row & 7) << 4;
                #pragma unroll
                for (int ct = 0; ct < 16; ++ct){
                    int off = row * 512 + (li + 16 * ct) * 2;
                    *(uint16_t*)(h256 + (off ^ rswz)) = bfc(fsilu(acc[rt][ct][r]));
                }
            }
        }
    };

    // ================= prologue: stage BE1 =================
    issueW128(W_be1, 0, 16);
    commitW(wb0, 2);
    __syncthreads();

    // ---- g0: BE1 (K=16 zero-padded to 32); A from edge_attr ----
    {
        bf16x8 aE0, aE1;
        {
            bf16x8 z = {0,0,0,0,0,0,0,0};
            aE0 = z; aE1 = z;
            if (lg < 2){
                int ea = e0 + li;      if (ea >= E) ea = E - 1;
                int eb = e0 + 16 + li; if (eb >= E) eb = E - 1;
                const float* pa = edge_attr + (size_t)ea * 16 + lg * 8;
                const float* pb = edge_attr + (size_t)eb * 16 + lg * 8;
                aE0 = pack8(*(const float4v*)pa, *(const float4v*)(pa + 4));
                aE1 = pack8(*(const float4v*)pb, *(const float4v*)(pb + 4));
            }
        }
        issueW128(W_be2, 0, 128);
        init128(b_be1);
        grp128(curbuf(), aE0, aE1);
        lnstore(g_be1, bb_be1);
        stepend(128);
    }

    // ---- g1..4: BE2 (A = e1 in bufE, in-place; per-kt reads precede lnstore) ----
    #pragma unroll
    for (int kt = 0; kt < 4; ++kt){
        if (kt < 3) issueW128(W_be2, (kt + 1) * 32, 128);
        else        issueW128(W_be3, 0, 128);
        if (kt == 0) init128(b_be2);
        grp128(curbuf(), eb_read8(li, kt), eb_read8(16 + li, kt));
        if (kt == 3) lnstore(g_be2, bb_be2);
        stepend(128);
    }
    // ---- g5..8: BE3 ----
    #pragma unroll
    for (int kt = 0; kt < 4; ++kt){
        if (kt < 3) issueW128(W_be3, (kt + 1) * 32, 128);
        else        issueW256(W_d1, 0);
        if (kt == 0) init128(b_be3);
        grp128(curbuf(), eb_read8(li, kt), eb_read8(16 + li, kt));
        if (kt == 3) lnstore(g_be3, bb_be3);      // e3 stays in bufE
        stepend(kt < 3 ? 128 : 256);
    }

    // ---- g9..12: D1 (128 -> 256), A from dual_emb (A-loads issued first) ----
    #pragma unroll
    for (int kt = 0; kt < 4; ++kt){
        float4v va0, va1, vb0, vb1;
        {
            int ea = e0 + li;      if (ea >= E) ea = E - 1;
            int eb = e0 + 16 + li; if (eb >= E) eb = E - 1;
            const float* pa = dual_emb + (size_t)ea * 128 + kt * 32 + lg * 8;
            const float* pb = dual_emb + (size_t)eb * 128 + kt * 32 + lg * 8;
            va0 = *(const float4v*)pa; va1 = *(const float4v*)(pa + 4);
            vb0 = *(const float4v*)pb; vb1 = *(const float4v*)(pb + 4);
        }
        if (kt < 3) issueW256(W_d1, (kt + 1) * 32);
        else        issueW256(W_d2, 0);
        if (kt == 0) init256(b_d1);
        grp256(curbuf(), pack8(va0, va1), pack8(vb0, vb1));
        if (kt == 3) silustore256();
        stepend(256);
    }

    // ---- g13..20: D2 (256 -> 256) + fused W_do dot -> dual_p ----
    #pragma unroll
    for (int kt = 0; kt < 8; ++kt){
        if (kt < 7) issueW256(W_d2, (kt + 1) * 32);
        else        issueW256(W_f1, 0);
        if (kt == 0) init256(b_d2);
        grp256(curbuf(), h2_read8(li, kt), h2_read8(16 + li, kt));
        if (kt == 7){
            float bdo0 = b_do[0];
            #pragma unroll
            for (int rt = 0; rt < 2; ++rt){
                #pragma unroll
                for (int r = 0; r < 4; ++r){
                    float s = 0.f;
                    #pragma unroll
                    for (int ct = 0; ct < 16; ++ct) s += fsilu(acc[rt][ct][r]) * W_do[li + 16 * ct];
                    s += __shfl_xor(s, 1); s += __shfl_xor(s, 2);
                    s += __shfl_xor(s, 4); s += __shfl_xor(s, 8);
                    if (li == 0) dpv[rt * 16 + lg * 4 + r] = fsigmoid(s + bdo0);
                }
            }
        }
        stepend(256);
    }

    // ---- g21..32: F1 (387 -> 256) ----
    {
        int s0 = sidx[li], s1 = sidx[16 + li];
        int d0 = didx[li], d1 = didx[16 + li];
        #pragma unroll
        for (int kt = 0; kt < 12; ++kt){
            bf16x8 a0, a1;
            if (kt < 8){
                int ra = (kt < 4) ? s0 : d0;
                int rb = (kt < 4) ? s1 : d1;
                int ko = (kt & 3) * 32 + lg * 8;
                const float* pa = node_emb + (size_t)ra * 128 + ko;
                const float* pb = node_emb + (size_t)rb * 128 + ko;
                float4v va0 = *(const float4v*)pa, va1 = *(const float4v*)(pa + 4);
                float4v vb0 = *(const float4v*)pb, vb1 = *(const float4v*)(pb + 4);
                a0 = pack8(va0, va1); a1 = pack8(vb0, vb1);
            } else {
                a0 = eb_read8(li, kt - 8); a1 = eb_read8(16 + li, kt - 8);
            }
            if (kt < 11) issueW256(W_f1, (kt + 1) * 32);
            else         issueW256(W_f2, 0);
            if (kt == 0){
                #pragma unroll
                for (int ct = 0; ct < 16; ++ct){
                    int col = li + 16 * ct;
                    float bv = b_f1[col];
                    float t0 = W_f1[384 * 256 + col];
                    float t1 = W_f1[385 * 256 + col];
                    float t2 = W_f1[386 * 256 + col];
                    #pragma unroll
                    for (int rt = 0; rt < 2; ++rt)
                        #pragma unroll
                        for (int r = 0; r < 4; ++r){
                            int row = rt * 16 + lg * 4 + r;
                            acc[rt][ct][r] = bv + dpv[row]*t0 + ps[row]*t1 + pd[row]*t2;
                        }
                }
            }
            grp256(curbuf(), a0, a1);
            if (kt == 11) silustore256();    // x1 overwrites h256
            stepend(256);
        }
    }

    // ---- g33..40: F2 (256 -> 256) + fused W_bo dot -> out ----
    #pragma unroll
    for (int kt = 0; kt < 8; ++kt){
        if (kt < 7) issueW256(W_f2, (kt + 1) * 32);
        if (kt == 0) init256(b_f2);
        grp256(curbuf(), h2_read8(li, kt), h2_read8(16 + li, kt));
        if (kt == 7){
            float bbo0 = b_bo[0];
            #pragma unroll
            for (int rt = 0; rt < 2; ++rt){
                #pragma unroll
                for (int r = 0; r < 4; ++r){
                    float s = 0.f;
                    #pragma unroll
                    for (int ct = 0; ct < 16; ++ct) s += fsilu(acc[rt][ct][r]) * W_bo[li + 16 * ct];
                    s += __shfl_xor(s, 1); s += __shfl_xor(s, 2);
                    s += __shfl_xor(s, 4); s += __shfl_xor(s, 8);
                    if (li == 0){
                        int e = e0 + rt * 16 + lg * 4 + r;
                        if (e < E) out[e] = s + bbo0;
                    }
                }
            }
        } else {
            stepend(256);
        }
    }
}

extern "C" void kernel_launch(void* const* d_in, const int* in_sizes, int n_in,
                              void* d_out, int out_size, void* d_ws, size_t ws_size,
                              hipStream_t stream) {
    const float* node_emb   = (const float*)d_in[0];
    const int*   edge_index = (const int*)d_in[1];
    const float* edge_attr  = (const float*)d_in[2];
    const float* dual_emb   = (const float*)d_in[3];
    const float* logits     = (const float*)d_in[4];
    const float* W_be1 = (const float*)d_in[5];
    const float* b_be1 = (const float*)d_in[6];
    const float* g_be1 = (const float*)d_in[7];
    const float* bb_be1= (const float*)d_in[8];
    const float* W_be2 = (const float*)d_in[9];
    const float* b_be2 = (const float*)d_in[10];
    const float* g_be2 = (const float*)d_in[11];
    const float* bb_be2= (const float*)d_in[12];
    const float* W_be3 = (const float*)d_in[13];
    const float* b_be3 = (const float*)d_in[14];
    const float* g_be3 = (const float*)d_in[15];
    const float* bb_be3= (const float*)d_in[16];
    const float* W_d1  = (const float*)d_in[17];
    const float* b_d1  = (const float*)d_in[18];
    const float* W_d2  = (const float*)d_in[19];
    const float* b_d2  = (const float*)d_in[20];
    const float* W_do  = (const float*)d_in[21];
    const float* b_do  = (const float*)d_in[22];
    const float* W_f1  = (const float*)d_in[23];
    const float* b_f1  = (const float*)d_in[24];
    const float* W_f2  = (const float*)d_in[25];
    const float* b_f2  = (const float*)d_in[26];
    const float* W_bo  = (const float*)d_in[27];
    const float* b_bo  = (const float*)d_in[28];
    float* out = (float*)d_out;

    int E = in_sizes[2] / 16;
    int nblocks = (E + 127) / 128;
    bond_fused_kernel<<<dim3(nblocks), dim3(256), 0, stream>>>(
        node_emb, edge_index, edge_attr, dual_emb, logits,
        W_be1, b_be1, g_be1, bb_be1,
        W_be2, b_be2, g_be2, bb_be2,
        W_be3, b_be3, g_be3, bb_be3,
        W_d1, b_d1, W_d2, b_d2, W_do, b_do,
        W_f1, b_f1, W_f2, b_f2, W_bo, b_bo,
        out, E);
}

// Round 5
// 1127.509 us; speedup vs baseline: 3.5183x; 1.3596x over previous
//
#include <hip/hip_runtime.h>
#include <hip/hip_bf16.h>
#include <stdint.h>

typedef __attribute__((ext_vector_type(8))) short bf16x8;
typedef __attribute__((ext_vector_type(4))) float f32x4;
typedef __attribute__((ext_vector_type(4))) float float4v;

__device__ __forceinline__ uint16_t bfc(float x){
    __hip_bfloat16 h = __float2bfloat16(x);
    return __builtin_bit_cast(uint16_t, h);
}
__device__ __forceinline__ uint32_t pk2(float a, float b){
    return (uint32_t)bfc(a) | ((uint32_t)bfc(b) << 16);
}
__device__ __forceinline__ float fsigmoid(float x){ return 1.0f / (1.0f + __expf(-x)); }
__device__ __forceinline__ float fsilu(float x){ return x * fsigmoid(x); }

__device__ __forceinline__ bf16x8 pack8(float4v lo, float4v hi){
    bf16x8 r;
    r[0]=(short)bfc(lo[0]); r[1]=(short)bfc(lo[1]);
    r[2]=(short)bfc(lo[2]); r[3]=(short)bfc(lo[3]);
    r[4]=(short)bfc(hi[0]); r[5]=(short)bfc(hi[1]);
    r[6]=(short)bfc(hi[2]); r[7]=(short)bfc(hi[3]);
    return r;
}

// LDS (135168 B, 1 block/CU, 512 threads = 8 waves = 2 waves/SIMD):
//   [0      .. 32768)  bufE : bf16[128][128] XOR-swz  (BE activations, per-wave 16 rows)
//   [32768  .. 98304)  h256 : bf16[128][256] XOR-swz  (256-wide activations)
//   [98304  ..131072)  wbuf : 2 x 16KB weight-frag chunk (double buffer)
//   [131072 ..135168)  misc : ps[128] pd[128] sidx[128] didx[128] dpp[2][128] bop[2][128]
#define LDS_TOTAL 135168

__global__ void __launch_bounds__(512, 1)
bond_fused_kernel(const float* __restrict__ node_emb, const int* __restrict__ edge_index,
                  const float* __restrict__ edge_attr, const float* __restrict__ dual_emb,
                  const float* __restrict__ logits,
                  const float* __restrict__ W_be1, const float* __restrict__ b_be1,
                  const float* __restrict__ g_be1, const float* __restrict__ bb_be1,
                  const float* __restrict__ W_be2, const float* __restrict__ b_be2,
                  const float* __restrict__ g_be2, const float* __restrict__ bb_be2,
                  const float* __restrict__ W_be3, const float* __restrict__ b_be3,
                  const float* __restrict__ g_be3, const float* __restrict__ bb_be3,
                  const float* __restrict__ W_d1, const float* __restrict__ b_d1,
                  const float* __restrict__ W_d2, const float* __restrict__ b_d2,
                  const float* __restrict__ W_do, const float* __restrict__ b_do,
                  const float* __restrict__ W_f1, const float* __restrict__ b_f1,
                  const float* __restrict__ W_f2, const float* __restrict__ b_f2,
                  const float* __restrict__ W_bo, const float* __restrict__ b_bo,
                  float* __restrict__ out, int E)
{
    __shared__ char lds[LDS_TOTAL];
    const int t    = threadIdx.x;
    const int wave = t >> 6;            // 0..7
    const int lane = t & 63;
    const int li   = lane & 15, lg = lane >> 4;
    const int eg   = wave >> 1;         // edge-group (32 edges) for 256-wide layers
    const int ch   = wave & 1;          // column half for 256-wide layers
    const int e0b  = blockIdx.x * 128;

    char* bufE = lds;
    char* h256 = lds + 32768;
    uint16_t* wb0 = (uint16_t*)(lds + 98304);
    uint16_t* wb1 = (uint16_t*)(lds + 114688);
    float* ps  = (float*)(lds + 131072);
    float* pd  = (float*)(lds + 131584);
    int* sidx  = (int*)(lds + 132096);
    int* didx  = (int*)(lds + 132608);
    float* dpp = (float*)(lds + 133120);   // [2][128] W_do partials
    float* bop = (float*)(lds + 134144);   // [2][128] W_bo partials

    // ---- gather: indices + atom sigmoids (threads 0..127) ----
    if (t < 128) {
        int e = e0b + t; if (e >= E) e = E - 1;
        int s_ = edge_index[e];
        int d_ = edge_index[E + e];
        sidx[t] = s_; didx[t] = d_;
        ps[t] = fsigmoid(logits[s_]);
        pd[t] = fsigmoid(logits[d_]);
    }

    // ================= weight staging (512 threads) =================
    // frag elem = fid*512 + ln*8 + j  <->  B[kbase + (ln>>4)*8 + j][fid*16 + (ln&15)]
    // thread: ln = lane, fid = wave (+8h) -> b128 commits wave-linear, conflict-free.
    float sr[2][8];
    auto issueW256 = [&](const float* W, int kbase){
        #pragma unroll
        for (int h = 0; h < 2; ++h){
            const float* p = W + (size_t)(kbase + lg * 8) * 256 + (wave + 8*h) * 16 + li;
            #pragma unroll
            for (int j = 0; j < 8; ++j) sr[h][j] = p[j * 256];
        }
    };
    auto issueW128 = [&](const float* W, int kbase, int K){
        const float* p = W + (size_t)(kbase + lg * 8) * 128 + wave * 16 + li;
        #pragma unroll
        for (int j = 0; j < 8; ++j)
            sr[0][j] = (kbase + lg * 8 + j < K) ? p[j * 128] : 0.f;
    };
    auto commitW = [&](uint16_t* dst, int nh){
        #pragma unroll
        for (int h = 0; h < 2; ++h){
            if (h < nh){
                uint4 w;
                w.x = pk2(sr[h][0], sr[h][1]); w.y = pk2(sr[h][2], sr[h][3]);
                w.z = pk2(sr[h][4], sr[h][5]); w.w = pk2(sr[h][6], sr[h][7]);
                *(uint4*)(dst + (wave + 8*h) * 512 + lane * 8) = w;
            }
        }
    };

    int cur = 0;
    auto stepend = [&](int mode){
        if (mode) commitW(cur ? wb0 : wb1, mode == 128 ? 1 : 2);
        __syncthreads();
        cur ^= 1;
    };
    auto curbuf = [&]() -> const uint16_t* { return cur ? wb1 : wb0; };

    // ================= compute =================
    f32x4 acc[2][8];    // 256-layers: [rt][ct] col=ch*128+ct*16+li; BE: acc[0][ct] col=ct*16+li

    auto ldf = [&](const uint16_t* w, int fid) -> bf16x8 {
        return *(const bf16x8*)(w + fid * 512 + lane * 8);
    };
    auto grpBE = [&](const uint16_t* w, bf16x8 a0){
        #pragma unroll
        for (int ct = 0; ct < 8; ++ct){
            bf16x8 b = ldf(w, ct);
            acc[0][ct] = __builtin_amdgcn_mfma_f32_16x16x32_bf16(a0, b, acc[0][ct], 0, 0, 0);
        }
    };
    auto grp256 = [&](const uint16_t* w, bf16x8 a0, bf16x8 a1){
        #pragma unroll
        for (int ct = 0; ct < 8; ++ct){
            bf16x8 b = ldf(w, ch * 8 + ct);
            acc[0][ct] = __builtin_amdgcn_mfma_f32_16x16x32_bf16(a0, b, acc[0][ct], 0, 0, 0);
            acc[1][ct] = __builtin_amdgcn_mfma_f32_16x16x32_bf16(a1, b, acc[1][ct], 0, 0, 0);
        }
    };
    auto initBE = [&](const float* b){
        #pragma unroll
        for (int ct = 0; ct < 8; ++ct){
            float bv = b[li + 16 * ct];
            f32x4 iv = {bv, bv, bv, bv};
            acc[0][ct] = iv;
        }
    };
    auto init256 = [&](const float* b){
        #pragma unroll
        for (int ct = 0; ct < 8; ++ct){
            float bv = b[ch * 128 + ct * 16 + li];
            f32x4 iv = {bv, bv, bv, bv};
            acc[0][ct] = iv; acc[1][ct] = iv;
        }
    };
    auto eb_read = [&](int row, int kt) -> bf16x8 {   // row = local 0..127
        int off = row * 256 + (kt * 32 + lg * 8) * 2;
        return *(const bf16x8*)(bufE + (off ^ ((row & 7) << 4)));
    };
    auto h2_read = [&](int row, int kt) -> bf16x8 {
        int off = row * 512 + (kt * 32 + lg * 8) * 2;
        return *(const bf16x8*)(h256 + (off ^ ((row & 7) << 4)));
    };
    auto lnstoreBE = [&](const float* g, const float* bb){
        #pragma unroll
        for (int r = 0; r < 4; ++r){
            float s = 0.f, q = 0.f;
            #pragma unroll
            for (int ct = 0; ct < 8; ++ct){ float v = acc[0][ct][r]; s += v; q += v*v; }
            s += __shfl_xor(s, 1); q += __shfl_xor(q, 1);
            s += __shfl_xor(s, 2); q += __shfl_xor(q, 2);
            s += __shfl_xor(s, 4); q += __shfl_xor(q, 4);
            s += __shfl_xor(s, 8); q += __shfl_xor(q, 8);
            float mu = s * 0.0078125f;
            float var = q * 0.0078125f - mu * mu;
            float rs = rsqrtf(var + 1e-5f);
            int row = wave * 16 + lg * 4 + r;
            int rswz = (row & 7) << 4;
            #pragma unroll
            for (int ct = 0; ct < 8; ++ct){
                int col = li + 16 * ct;
                float v = (acc[0][ct][r] - mu) * rs * g[col] + bb[col];
                int off = row * 256 + col * 2;
                *(uint16_t*)(bufE + (off ^ rswz)) = bfc(fsilu(v));
            }
        }
    };
    auto silustore256 = [&](){
        #pragma unroll
        for (int rt = 0; rt < 2; ++rt){
            #pragma unroll
            for (int r = 0; r < 4; ++r){
                int row = eg * 32 + rt * 16 + lg * 4 + r;
                int rswz = (row & 7) << 4;
                #pragma unroll
                for (int ct = 0; ct < 8; ++ct){
                    int off = row * 512 + (ch * 128 + ct * 16 + li) * 2;
                    *(uint16_t*)(h256 + (off ^ rswz)) = bfc(fsilu(acc[rt][ct][r]));
                }
            }
        }
    };

    // ================= prologue: stage BE1 =================
    issueW128(W_be1, 0, 16);
    commitW(wb0, 1);
    __syncthreads();

    // ---- g0: BE1 (K=16 pad 32), per wave 16 edges, A from edge_attr ----
    {
        bf16x8 aE = {0,0,0,0,0,0,0,0};
        if (lg < 2){
            int ea = e0b + wave * 16 + li; if (ea >= E) ea = E - 1;
            const float* pa = edge_attr + (size_t)ea * 16 + lg * 8;
            aE = pack8(*(const float4v*)pa, *(const float4v*)(pa + 4));
        }
        issueW128(W_be2, 0, 128);
        initBE(b_be1);
        grpBE(curbuf(), aE);
        lnstoreBE(g_be1, bb_be1);
        stepend(128);
    }

    // ---- g1..4: BE2 ----
    #pragma unroll 1
    for (int kt = 0; kt < 4; ++kt){
        if (kt < 3) issueW128(W_be2, (kt + 1) * 32, 128);
        else        issueW128(W_be3, 0, 128);
        if (kt == 0) initBE(b_be2);
        grpBE(curbuf(), eb_read(wave * 16 + li, kt));
        if (kt == 3) lnstoreBE(g_be2, bb_be2);
        stepend(128);
    }
    // ---- g5..8: BE3 ----
    #pragma unroll 1
    for (int kt = 0; kt < 4; ++kt){
        if (kt < 3) issueW128(W_be3, (kt + 1) * 32, 128);
        else        issueW256(W_d1, 0);
        if (kt == 0) initBE(b_be3);
        grpBE(curbuf(), eb_read(wave * 16 + li, kt));
        if (kt == 3) lnstoreBE(g_be3, bb_be3);       // e3 stays in bufE
        stepend(kt < 3 ? 128 : 256);
    }

    // ---- g9..12: D1 (128 -> 256), A from dual_emb ----
    #pragma unroll 1
    for (int kt = 0; kt < 4; ++kt){
        float4v va0, va1, vb0, vb1;
        {
            int ea = e0b + eg * 32 + li;      if (ea >= E) ea = E - 1;
            int eb = e0b + eg * 32 + 16 + li; if (eb >= E) eb = E - 1;
            const float* pa = dual_emb + (size_t)ea * 128 + kt * 32 + lg * 8;
            const float* pb = dual_emb + (size_t)eb * 128 + kt * 32 + lg * 8;
            va0 = *(const float4v*)pa; va1 = *(const float4v*)(pa + 4);
            vb0 = *(const float4v*)pb; vb1 = *(const float4v*)(pb + 4);
        }
        if (kt < 3) issueW256(W_d1, (kt + 1) * 32);
        else        issueW256(W_d2, 0);
        if (kt == 0) init256(b_d1);
        grp256(curbuf(), pack8(va0, va1), pack8(vb0, vb1));
        if (kt == 3) silustore256();
        stepend(256);
    }

    // ---- g13..20: D2 (256 -> 256) + W_do partial dot ----
    #pragma unroll 1
    for (int kt = 0; kt < 8; ++kt){
        if (kt < 7) issueW256(W_d2, (kt + 1) * 32);
        else        issueW256(W_f1, 0);
        if (kt == 0) init256(b_d2);
        grp256(curbuf(), h2_read(eg * 32 + li, kt), h2_read(eg * 32 + 16 + li, kt));
        if (kt == 7){
            #pragma unroll
            for (int rt = 0; rt < 2; ++rt){
                #pragma unroll
                for (int r = 0; r < 4; ++r){
                    float s = 0.f;
                    #pragma unroll
                    for (int ct = 0; ct < 8; ++ct)
                        s += fsilu(acc[rt][ct][r]) * W_do[ch * 128 + ct * 16 + li];
                    s += __shfl_xor(s, 1); s += __shfl_xor(s, 2);
                    s += __shfl_xor(s, 4); s += __shfl_xor(s, 8);
                    if (li == 0) dpp[ch * 128 + eg * 32 + rt * 16 + lg * 4 + r] = s;
                }
            }
        }
        stepend(256);
    }

    // ---- g21..32: F1 (387 -> 256) ----
    {
        int s0 = sidx[eg * 32 + li],      s1 = sidx[eg * 32 + 16 + li];
        int d0 = didx[eg * 32 + li],      d1 = didx[eg * 32 + 16 + li];
        #pragma unroll 1
        for (int kt = 0; kt < 12; ++kt){
            bf16x8 a0, a1;
            if (kt < 8){
                int ra = (kt < 4) ? s0 : d0;
                int rb = (kt < 4) ? s1 : d1;
                int ko = (kt & 3) * 32 + lg * 8;
                const float* pa = node_emb + (size_t)ra * 128 + ko;
                const float* pb = node_emb + (size_t)rb * 128 + ko;
                a0 = pack8(*(const float4v*)pa, *(const float4v*)(pa + 4));
                a1 = pack8(*(const float4v*)pb, *(const float4v*)(pb + 4));
            } else {
                a0 = eb_read(eg * 32 + li, kt - 8);
                a1 = eb_read(eg * 32 + 16 + li, kt - 8);
            }
            if (kt < 11) issueW256(W_f1, (kt + 1) * 32);
            else         issueW256(W_f2, 0);
            if (kt == 0){
                float bdo0 = b_do[0];
                float dpv_[2][4], psr[2][4], pdr[2][4];
                #pragma unroll
                for (int rt = 0; rt < 2; ++rt)
                    #pragma unroll
                    for (int r = 0; r < 4; ++r){
                        int row = eg * 32 + rt * 16 + lg * 4 + r;
                        dpv_[rt][r] = fsigmoid(dpp[row] + dpp[128 + row] + bdo0);
                        psr[rt][r] = ps[row]; pdr[rt][r] = pd[row];
                    }
                #pragma unroll
                for (int ct = 0; ct < 8; ++ct){
                    int col = ch * 128 + ct * 16 + li;
                    float bv = b_f1[col];
                    float t0 = W_f1[384 * 256 + col];
                    float t1 = W_f1[385 * 256 + col];
                    float t2 = W_f1[386 * 256 + col];
                    #pragma unroll
                    for (int rt = 0; rt < 2; ++rt)
                        #pragma unroll
                        for (int r = 0; r < 4; ++r)
                            acc[rt][ct][r] = bv + dpv_[rt][r]*t0 + psr[rt][r]*t1 + pdr[rt][r]*t2;
                }
            }
            grp256(curbuf(), a0, a1);
            if (kt == 11) silustore256();    // x1 overwrites h256
            stepend(256);
        }
    }

    // ---- g33..40: F2 (256 -> 256) + W_bo partial dot -> out ----
    #pragma unroll 1
    for (int kt = 0; kt < 8; ++kt){
        if (kt < 7) issueW256(W_f2, (kt + 1) * 32);
        if (kt == 0) init256(b_f2);
        grp256(curbuf(), h2_read(eg * 32 + li, kt), h2_read(eg * 32 + 16 + li, kt));
        if (kt == 7){
            #pragma unroll
            for (int rt = 0; rt < 2; ++rt){
                #pragma unroll
                for (int r = 0; r < 4; ++r){
                    float s = 0.f;
                    #pragma unroll
                    for (int ct = 0; ct < 8; ++ct)
                        s += fsilu(acc[rt][ct][r]) * W_bo[ch * 128 + ct * 16 + li];
                    s += __shfl_xor(s, 1); s += __shfl_xor(s, 2);
                    s += __shfl_xor(s, 4); s += __shfl_xor(s, 8);
                    if (li == 0) bop[ch * 128 + eg * 32 + rt * 16 + lg * 4 + r] = s;
                }
            }
        } else {
            stepend(256);
        }
    }
    __syncthreads();
    if (t < 128){
        int e = e0b + t;
        if (e < E) out[e] = bop[t] + bop[128 + t] + b_bo[0];
    }
}

extern "C" void kernel_launch(void* const* d_in, const int* in_sizes, int n_in,
                              void* d_out, int out_size, void* d_ws, size_t ws_size,
                              hipStream_t stream) {
    const float* node_emb   = (const float*)d_in[0];
    const int*   edge_index = (const int*)d_in[1];
    const float* edge_attr  = (const float*)d_in[2];
    const float* dual_emb   = (const float*)d_in[3];
    const float* logits     = (const float*)d_in[4];
    const float* W_be1 = (const float*)d_in[5];
    const float* b_be1 = (const float*)d_in[6];
    const float* g_be1 = (const float*)d_in[7];
    const float* bb_be1= (const float*)d_in[8];
    const float* W_be2 = (const float*)d_in[9];
    const float* b_be2 = (const float*)d_in[10];
    const float* g_be2 = (const float*)d_in[11];
    const float* bb_be2= (const float*)d_in[12];
    const float* W_be3 = (const float*)d_in[13];
    const float* b_be3 = (const float*)d_in[14];
    const float* g_be3 = (const float*)d_in[15];
    const float* bb_be3= (const float*)d_in[16];
    const float* W_d1  = (const float*)d_in[17];
    const float* b_d1  = (const float*)d_in[18];
    const float* W_d2  = (const float*)d_in[19];
    const float* b_d2  = (const float*)d_in[20];
    const float* W_do  = (const float*)d_in[21];
    const float* b_do  = (const float*)d_in[22];
    const float* W_f1  = (const float*)d_in[23];
    const float* b_f1  = (const float*)d_in[24];
    const float* W_f2  = (const float*)d_in[25];
    const float* b_f2  = (const float*)d_in[26];
    const float* W_bo  = (const float*)d_in[27];
    const float* b_bo  = (const float*)d_in[28];
    float* out = (float*)d_out;

    int E = in_sizes[2] / 16;
    int nblocks = (E + 127) / 128;
    bond_fused_kernel<<<dim3(nblocks), dim3(512), 0, stream>>>(
        node_emb, edge_index, edge_attr, dual_emb, logits,
        W_be1, b_be1, g_be1, bb_be1,
        W_be2, b_be2, g_be2, bb_be2,
        W_be3, b_be3, g_be3, bb_be3,
        W_d1, b_d1, W_d2, b_d2, W_do, b_do,
        W_f1, b_f1, W_f2, b_f2, W_bo, b_bo,
        out, E);
}

// Round 6
// 936.589 us; speedup vs baseline: 4.2355x; 1.2038x over previous
//
#include <hip/hip_runtime.h>
#include <hip/hip_bf16.h>
#include <stdint.h>

typedef __attribute__((ext_vector_type(8))) short bf16x8;
typedef __attribute__((ext_vector_type(4))) float f32x4;
typedef __attribute__((ext_vector_type(4))) float float4v;

__device__ __forceinline__ uint16_t bfc(float x){
    __hip_bfloat16 h = __float2bfloat16(x);
    return __builtin_bit_cast(uint16_t, h);
}
__device__ __forceinline__ uint32_t pk2(float a, float b){
    return (uint32_t)bfc(a) | ((uint32_t)bfc(b) << 16);
}
__device__ __forceinline__ float fsigmoid(float x){ return 1.0f / (1.0f + __expf(-x)); }
__device__ __forceinline__ float fsilu(float x){ return x * fsigmoid(x); }

__device__ __forceinline__ bf16x8 pack8(float4v lo, float4v hi){
    bf16x8 r;
    r[0]=(short)bfc(lo[0]); r[1]=(short)bfc(lo[1]);
    r[2]=(short)bfc(lo[2]); r[3]=(short)bfc(lo[3]);
    r[4]=(short)bfc(hi[0]); r[5]=(short)bfc(hi[1]);
    r[6]=(short)bfc(hi[2]); r[7]=(short)bfc(hi[3]);
    return r;
}

// LDS (135168 B, 1 block/CU, 512 threads = 8 waves = 2 waves/SIMD):
//   [0      .. 32768)  bufE : bf16[128][128] XOR-swz  (BE activations, per-wave 16 rows)
//   [32768  .. 98304)  h256 : bf16[128][256] XOR-swz  (256-wide activations)
//   [98304  ..131072)  wbuf : 2 x 16KB weight-frag chunk (double buffer)
//   [131072 ..135168)  misc : ps[128] pd[128] sidx[128] didx[128] dpp[2][128] bop[2][128]
#define LDS_TOTAL 135168

// waves_per_eu(2,2): LDS already forces 1 block/CU = 2 waves/SIMD; let the
// register allocator use the full 256-VGPR budget for that occupancy
// (default heuristic capped at 128 and spilled ~85KB/block -> 430MB WRITE_SIZE).
__global__ void __launch_bounds__(512) __attribute__((amdgpu_waves_per_eu(2, 2)))
bond_fused_kernel(const float* __restrict__ node_emb, const int* __restrict__ edge_index,
                  const float* __restrict__ edge_attr, const float* __restrict__ dual_emb,
                  const float* __restrict__ logits,
                  const float* __restrict__ W_be1, const float* __restrict__ b_be1,
                  const float* __restrict__ g_be1, const float* __restrict__ bb_be1,
                  const float* __restrict__ W_be2, const float* __restrict__ b_be2,
                  const float* __restrict__ g_be2, const float* __restrict__ bb_be2,
                  const float* __restrict__ W_be3, const float* __restrict__ b_be3,
                  const float* __restrict__ g_be3, const float* __restrict__ bb_be3,
                  const float* __restrict__ W_d1, const float* __restrict__ b_d1,
                  const float* __restrict__ W_d2, const float* __restrict__ b_d2,
                  const float* __restrict__ W_do, const float* __restrict__ b_do,
                  const float* __restrict__ W_f1, const float* __restrict__ b_f1,
                  const float* __restrict__ W_f2, const float* __restrict__ b_f2,
                  const float* __restrict__ W_bo, const float* __restrict__ b_bo,
                  float* __restrict__ out, int E)
{
    __shared__ char lds[LDS_TOTAL];
    const int t    = threadIdx.x;
    const int wave = t >> 6;            // 0..7
    const int lane = t & 63;
    const int li   = lane & 15, lg = lane >> 4;
    const int eg   = wave >> 1;         // edge-group (32 edges) for 256-wide layers
    const int ch   = wave & 1;          // column half for 256-wide layers
    const int e0b  = blockIdx.x * 128;

    char* bufE = lds;
    char* h256 = lds + 32768;
    uint16_t* wb0 = (uint16_t*)(lds + 98304);
    uint16_t* wb1 = (uint16_t*)(lds + 114688);
    float* ps  = (float*)(lds + 131072);
    float* pd  = (float*)(lds + 131584);
    int* sidx  = (int*)(lds + 132096);
    int* didx  = (int*)(lds + 132608);
    float* dpp = (float*)(lds + 133120);   // [2][128] W_do partials
    float* bop = (float*)(lds + 134144);   // [2][128] W_bo partials

    // ---- gather: indices + atom sigmoids (threads 0..127) ----
    if (t < 128) {
        int e = e0b + t; if (e >= E) e = E - 1;
        int s_ = edge_index[e];
        int d_ = edge_index[E + e];
        sidx[t] = s_; didx[t] = d_;
        ps[t] = fsigmoid(logits[s_]);
        pd[t] = fsigmoid(logits[d_]);
    }

    // ================= weight staging (512 threads) =================
    // frag elem = fid*512 + ln*8 + j  <->  B[kbase + (ln>>4)*8 + j][fid*16 + (ln&15)]
    // thread: ln = lane, fid = wave (+8h) -> b128 commits wave-linear, conflict-free.
    float sr[2][8];
    auto issueW256 = [&](const float* W, int kbase){
        #pragma unroll
        for (int h = 0; h < 2; ++h){
            const float* p = W + (size_t)(kbase + lg * 8) * 256 + (wave + 8*h) * 16 + li;
            #pragma unroll
            for (int j = 0; j < 8; ++j) sr[h][j] = p[j * 256];
        }
    };
    auto issueW128 = [&](const float* W, int kbase, int K){
        const float* p = W + (size_t)(kbase + lg * 8) * 128 + wave * 16 + li;
        #pragma unroll
        for (int j = 0; j < 8; ++j)
            sr[0][j] = (kbase + lg * 8 + j < K) ? p[j * 128] : 0.f;
    };
    auto commitW = [&](uint16_t* dst, int nh){
        #pragma unroll
        for (int h = 0; h < 2; ++h){
            if (h < nh){
                uint4 w;
                w.x = pk2(sr[h][0], sr[h][1]); w.y = pk2(sr[h][2], sr[h][3]);
                w.z = pk2(sr[h][4], sr[h][5]); w.w = pk2(sr[h][6], sr[h][7]);
                *(uint4*)(dst + (wave + 8*h) * 512 + lane * 8) = w;
            }
        }
    };

    int cur = 0;
    auto stepend = [&](int mode){
        if (mode) commitW(cur ? wb0 : wb1, mode == 128 ? 1 : 2);
        __syncthreads();
        cur ^= 1;
    };
    auto curbuf = [&]() -> const uint16_t* { return cur ? wb1 : wb0; };

    // ================= compute =================
    f32x4 acc[2][8];    // 256-layers: [rt][ct] col=ch*128+ct*16+li; BE: acc[0][ct] col=ct*16+li

    auto ldf = [&](const uint16_t* w, int fid) -> bf16x8 {
        return *(const bf16x8*)(w + fid * 512 + lane * 8);
    };
    auto grpBE = [&](const uint16_t* w, bf16x8 a0){
        #pragma unroll
        for (int ct = 0; ct < 8; ++ct){
            bf16x8 b = ldf(w, ct);
            acc[0][ct] = __builtin_amdgcn_mfma_f32_16x16x32_bf16(a0, b, acc[0][ct], 0, 0, 0);
        }
    };
    auto grp256 = [&](const uint16_t* w, bf16x8 a0, bf16x8 a1){
        #pragma unroll
        for (int ct = 0; ct < 8; ++ct){
            bf16x8 b = ldf(w, ch * 8 + ct);
            acc[0][ct] = __builtin_amdgcn_mfma_f32_16x16x32_bf16(a0, b, acc[0][ct], 0, 0, 0);
            acc[1][ct] = __builtin_amdgcn_mfma_f32_16x16x32_bf16(a1, b, acc[1][ct], 0, 0, 0);
        }
    };
    auto initBE = [&](const float* b){
        #pragma unroll
        for (int ct = 0; ct < 8; ++ct){
            float bv = b[li + 16 * ct];
            f32x4 iv = {bv, bv, bv, bv};
            acc[0][ct] = iv;
        }
    };
    auto init256 = [&](const float* b){
        #pragma unroll
        for (int ct = 0; ct < 8; ++ct){
            float bv = b[ch * 128 + ct * 16 + li];
            f32x4 iv = {bv, bv, bv, bv};
            acc[0][ct] = iv; acc[1][ct] = iv;
        }
    };
    auto eb_read = [&](int row, int kt) -> bf16x8 {   // row = local 0..127
        int off = row * 256 + (kt * 32 + lg * 8) * 2;
        return *(const bf16x8*)(bufE + (off ^ ((row & 7) << 4)));
    };
    auto h2_read = [&](int row, int kt) -> bf16x8 {
        int off = row * 512 + (kt * 32 + lg * 8) * 2;
        return *(const bf16x8*)(h256 + (off ^ ((row & 7) << 4)));
    };
    auto lnstoreBE = [&](const float* g, const float* bb){
        #pragma unroll
        for (int r = 0; r < 4; ++r){
            float s = 0.f, q = 0.f;
            #pragma unroll
            for (int ct = 0; ct < 8; ++ct){ float v = acc[0][ct][r]; s += v; q += v*v; }
            s += __shfl_xor(s, 1); q += __shfl_xor(q, 1);
            s += __shfl_xor(s, 2); q += __shfl_xor(q, 2);
            s += __shfl_xor(s, 4); q += __shfl_xor(q, 4);
            s += __shfl_xor(s, 8); q += __shfl_xor(q, 8);
            float mu = s * 0.0078125f;
            float var = q * 0.0078125f - mu * mu;
            float rs = rsqrtf(var + 1e-5f);
            int row = wave * 16 + lg * 4 + r;
            int rswz = (row & 7) << 4;
            #pragma unroll
            for (int ct = 0; ct < 8; ++ct){
                int col = li + 16 * ct;
                float v = (acc[0][ct][r] - mu) * rs * g[col] + bb[col];
                int off = row * 256 + col * 2;
                *(uint16_t*)(bufE + (off ^ rswz)) = bfc(fsilu(v));
            }
        }
    };
    auto silustore256 = [&](){
        #pragma unroll
        for (int rt = 0; rt < 2; ++rt){
            #pragma unroll
            for (int r = 0; r < 4; ++r){
                int row = eg * 32 + rt * 16 + lg * 4 + r;
                int rswz = (row & 7) << 4;
                #pragma unroll
                for (int ct = 0; ct < 8; ++ct){
                    int off = row * 512 + (ch * 128 + ct * 16 + li) * 2;
                    *(uint16_t*)(h256 + (off ^ rswz)) = bfc(fsilu(acc[rt][ct][r]));
                }
            }
        }
    };

    // ================= prologue: stage BE1 =================
    issueW128(W_be1, 0, 16);
    commitW(wb0, 1);
    __syncthreads();

    // ---- g0: BE1 (K=16 pad 32), per wave 16 edges, A from edge_attr ----
    {
        bf16x8 aE = {0,0,0,0,0,0,0,0};
        if (lg < 2){
            int ea = e0b + wave * 16 + li; if (ea >= E) ea = E - 1;
            const float* pa = edge_attr + (size_t)ea * 16 + lg * 8;
            aE = pack8(*(const float4v*)pa, *(const float4v*)(pa + 4));
        }
        issueW128(W_be2, 0, 128);
        initBE(b_be1);
        grpBE(curbuf(), aE);
        lnstoreBE(g_be1, bb_be1);
        stepend(128);
    }

    // ---- g1..4: BE2 ----
    initBE(b_be2);
    #pragma unroll 1
    for (int kt = 0; kt < 4; ++kt){
        if (kt < 3) issueW128(W_be2, (kt + 1) * 32, 128);
        else        issueW128(W_be3, 0, 128);
        grpBE(curbuf(), eb_read(wave * 16 + li, kt));
        if (kt == 3) lnstoreBE(g_be2, bb_be2);
        stepend(128);
    }
    // ---- g5..8: BE3 ----
    initBE(b_be3);
    #pragma unroll 1
    for (int kt = 0; kt < 4; ++kt){
        if (kt < 3) issueW128(W_be3, (kt + 1) * 32, 128);
        else        issueW256(W_d1, 0);
        grpBE(curbuf(), eb_read(wave * 16 + li, kt));
        if (kt == 3) lnstoreBE(g_be3, bb_be3);       // e3 stays in bufE
        stepend(kt < 3 ? 128 : 256);
    }

    // ---- g9..12: D1 (128 -> 256), A from dual_emb ----
    init256(b_d1);
    #pragma unroll 1
    for (int kt = 0; kt < 4; ++kt){
        float4v va0, va1, vb0, vb1;
        {
            int ea = e0b + eg * 32 + li;      if (ea >= E) ea = E - 1;
            int eb = e0b + eg * 32 + 16 + li; if (eb >= E) eb = E - 1;
            const float* pa = dual_emb + (size_t)ea * 128 + kt * 32 + lg * 8;
            const float* pb = dual_emb + (size_t)eb * 128 + kt * 32 + lg * 8;
            va0 = *(const float4v*)pa; va1 = *(const float4v*)(pa + 4);
            vb0 = *(const float4v*)pb; vb1 = *(const float4v*)(pb + 4);
        }
        if (kt < 3) issueW256(W_d1, (kt + 1) * 32);
        else        issueW256(W_d2, 0);
        grp256(curbuf(), pack8(va0, va1), pack8(vb0, vb1));
        if (kt == 3) silustore256();
        stepend(256);
    }

    // ---- g13..20: D2 (256 -> 256) + W_do partial dot ----
    init256(b_d2);
    #pragma unroll 1
    for (int kt = 0; kt < 8; ++kt){
        if (kt < 7) issueW256(W_d2, (kt + 1) * 32);
        else        issueW256(W_f1, 0);
        grp256(curbuf(), h2_read(eg * 32 + li, kt), h2_read(eg * 32 + 16 + li, kt));
        if (kt == 7){
            #pragma unroll
            for (int rt = 0; rt < 2; ++rt){
                #pragma unroll
                for (int r = 0; r < 4; ++r){
                    float s = 0.f;
                    #pragma unroll
                    for (int ct = 0; ct < 8; ++ct)
                        s += fsilu(acc[rt][ct][r]) * W_do[ch * 128 + ct * 16 + li];
                    s += __shfl_xor(s, 1); s += __shfl_xor(s, 2);
                    s += __shfl_xor(s, 4); s += __shfl_xor(s, 8);
                    if (li == 0) dpp[ch * 128 + eg * 32 + rt * 16 + lg * 4 + r] = s;
                }
            }
        }
        stepend(256);
    }

    // ---- g21..32: F1 (387 -> 256) ----
    {
        // acc init with bias + {dual_p, p_src, p_dst} features (rows 384..386),
        // hoisted out of the kt loop to shorten live ranges.
        {
            float bdo0 = b_do[0];
            #pragma unroll
            for (int ct = 0; ct < 8; ++ct){
                int col = ch * 128 + ct * 16 + li;
                float bv = b_f1[col];
                float t0 = W_f1[384 * 256 + col];
                float t1 = W_f1[385 * 256 + col];
                float t2 = W_f1[386 * 256 + col];
                #pragma unroll
                for (int rt = 0; rt < 2; ++rt)
                    #pragma unroll
                    for (int r = 0; r < 4; ++r){
                        int row = eg * 32 + rt * 16 + lg * 4 + r;
                        float dv = fsigmoid(dpp[row] + dpp[128 + row] + bdo0);
                        acc[rt][ct][r] = bv + dv*t0 + ps[row]*t1 + pd[row]*t2;
                    }
            }
        }
        int s0 = sidx[eg * 32 + li],      s1 = sidx[eg * 32 + 16 + li];
        int d0 = didx[eg * 32 + li],      d1 = didx[eg * 32 + 16 + li];
        #pragma unroll 1
        for (int kt = 0; kt < 12; ++kt){
            bf16x8 a0, a1;
            if (kt < 8){
                int ra = (kt < 4) ? s0 : d0;
                int rb = (kt < 4) ? s1 : d1;
                int ko = (kt & 3) * 32 + lg * 8;
                const float* pa = node_emb + (size_t)ra * 128 + ko;
                const float* pb = node_emb + (size_t)rb * 128 + ko;
                a0 = pack8(*(const float4v*)pa, *(const float4v*)(pa + 4));
                a1 = pack8(*(const float4v*)pb, *(const float4v*)(pb + 4));
            } else {
                a0 = eb_read(eg * 32 + li, kt - 8);
                a1 = eb_read(eg * 32 + 16 + li, kt - 8);
            }
            if (kt < 11) issueW256(W_f1, (kt + 1) * 32);
            else         issueW256(W_f2, 0);
            grp256(curbuf(), a0, a1);
            if (kt == 11) silustore256();    // x1 overwrites h256
            stepend(256);
        }
    }

    // ---- g33..40: F2 (256 -> 256) + W_bo partial dot -> out ----
    init256(b_f2);
    #pragma unroll 1
    for (int kt = 0; kt < 8; ++kt){
        if (kt < 7) issueW256(W_f2, (kt + 1) * 32);
        grp256(curbuf(), h2_read(eg * 32 + li, kt), h2_read(eg * 32 + 16 + li, kt));
        if (kt == 7){
            #pragma unroll
            for (int rt = 0; rt < 2; ++rt){
                #pragma unroll
                for (int r = 0; r < 4; ++r){
                    float s = 0.f;
                    #pragma unroll
                    for (int ct = 0; ct < 8; ++ct)
                        s += fsilu(acc[rt][ct][r]) * W_bo[ch * 128 + ct * 16 + li];
                    s += __shfl_xor(s, 1); s += __shfl_xor(s, 2);
                    s += __shfl_xor(s, 4); s += __shfl_xor(s, 8);
                    if (li == 0) bop[ch * 128 + eg * 32 + rt * 16 + lg * 4 + r] = s;
                }
            }
        } else {
            stepend(256);
        }
    }
    __syncthreads();
    if (t < 128){
        int e = e0b + t;
        if (e < E) out[e] = bop[t] + bop[128 + t] + b_bo[0];
    }
}

extern "C" void kernel_launch(void* const* d_in, const int* in_sizes, int n_in,
                              void* d_out, int out_size, void* d_ws, size_t ws_size,
                              hipStream_t stream) {
    const float* node_emb   = (const float*)d_in[0];
    const int*   edge_index = (const int*)d_in[1];
    const float* edge_attr  = (const float*)d_in[2];
    const float* dual_emb   = (const float*)d_in[3];
    const float* logits     = (const float*)d_in[4];
    const float* W_be1 = (const float*)d_in[5];
    const float* b_be1 = (const float*)d_in[6];
    const float* g_be1 = (const float*)d_in[7];
    const float* bb_be1= (const float*)d_in[8];
    const float* W_be2 = (const float*)d_in[9];
    const float* b_be2 = (const float*)d_in[10];
    const float* g_be2 = (const float*)d_in[11];
    const float* bb_be2= (const float*)d_in[12];
    const float* W_be3 = (const float*)d_in[13];
    const float* b_be3 = (const float*)d_in[14];
    const float* g_be3 = (const float*)d_in[15];
    const float* bb_be3= (const float*)d_in[16];
    const float* W_d1  = (const float*)d_in[17];
    const float* b_d1  = (const float*)d_in[18];
    const float* W_d2  = (const float*)d_in[19];
    const float* b_d2  = (const float*)d_in[20];
    const float* W_do  = (const float*)d_in[21];
    const float* b_do  = (const float*)d_in[22];
    const float* W_f1  = (const float*)d_in[23];
    const float* b_f1  = (const float*)d_in[24];
    const float* W_f2  = (const float*)d_in[25];
    const float* b_f2  = (const float*)d_in[26];
    const float* W_bo  = (const float*)d_in[27];
    const float* b_bo  = (const float*)d_in[28];
    float* out = (float*)d_out;

    int E = in_sizes[2] / 16;
    int nblocks = (E + 127) / 128;
    bond_fused_kernel<<<dim3(nblocks), dim3(512), 0, stream>>>(
        node_emb, edge_index, edge_attr, dual_emb, logits,
        W_be1, b_be1, g_be1, bb_be1,
        W_be2, b_be2, g_be2, bb_be2,
        W_be3, b_be3, g_be3, bb_be3,
        W_d1, b_d1, W_d2, b_d2, W_do, b_do,
        W_f1, b_f1, W_f2, b_f2, W_bo, b_bo,
        out, E);
}

// Round 7
// 774.153 us; speedup vs baseline: 5.1243x; 1.2098x over previous
//
#include <hip/hip_runtime.h>
#include <hip/hip_bf16.h>
#include <stdint.h>

typedef __attribute__((ext_vector_type(8))) short bf16x8;
typedef __attribute__((ext_vector_type(4))) float f32x4;
typedef __attribute__((ext_vector_type(4))) float float4v;

__device__ __forceinline__ uint16_t bfc(float x){
    __hip_bfloat16 h = __float2bfloat16(x);
    return __builtin_bit_cast(uint16_t, h);
}
__device__ __forceinline__ uint32_t pk2(float a, float b){
    return (uint32_t)bfc(a) | ((uint32_t)bfc(b) << 16);
}
__device__ __forceinline__ float fsigmoid(float x){ return 1.0f / (1.0f + __expf(-x)); }
__device__ __forceinline__ float fsilu(float x){ return x * fsigmoid(x); }

__device__ __forceinline__ bf16x8 pack8(float4v lo, float4v hi){
    bf16x8 r;
    r[0]=(short)bfc(lo[0]); r[1]=(short)bfc(lo[1]);
    r[2]=(short)bfc(lo[2]); r[3]=(short)bfc(lo[3]);
    r[4]=(short)bfc(hi[0]); r[5]=(short)bfc(hi[1]);
    r[6]=(short)bfc(hi[2]); r[7]=(short)bfc(hi[3]);
    return r;
}

// ---------------- weight prep (R2-validated fragpos map) ----------------
#define SZ_BE1 4096
#define SZ_128 16384
#define SZ_D1  32768
#define SZ_D2  65536
#define SZ_F1  98304
#define OFF_BE1 0
#define OFF_BE2 (OFF_BE1 + SZ_BE1)    // 4096
#define OFF_BE3 (OFF_BE2 + SZ_128)    // 20480
#define OFF_D1  (OFF_BE3 + SZ_128)    // 36864
#define OFF_D2  (OFF_D1 + SZ_D1)      // 69632
#define OFF_F1  (OFF_D2 + SZ_D2)      // 135168
#define OFF_F2  (OFF_F1 + SZ_F1)      // 233472
#define WS_ELEMS (OFF_F2 + SZ_D2)     // 299008 bf16 elems = 598016 B

__device__ __forceinline__ int fragpos(int k, int c, int OUT){
    int kt = k >> 5, ct = c >> 4;
    int fid = kt * (OUT >> 4) + ct;
    int ln = ((k & 31) >> 3) * 16 + (c & 15);
    return fid * 512 + ln * 8 + (k & 7);
}

__global__ void __launch_bounds__(256)
prep_w(const float* __restrict__ Wbe1, const float* __restrict__ Wbe2,
       const float* __restrict__ Wbe3, const float* __restrict__ Wd1,
       const float* __restrict__ Wd2,  const float* __restrict__ Wf1,
       const float* __restrict__ Wf2,  uint16_t* __restrict__ ws){
    int t = blockIdx.x * 256 + threadIdx.x;
    if (t >= WS_ELEMS) return;
    if (t < OFF_BE2) {                        // be1: K padded 16 -> 32
        int u = t;            int k = u >> 7, c = u & 127;
        float v = (k < 16) ? Wbe1[k * 128 + c] : 0.0f;
        ws[OFF_BE1 + fragpos(k, c, 128)] = bfc(v);
    } else if (t < OFF_BE3) {
        int u = t - OFF_BE2;  int k = u >> 7, c = u & 127;
        ws[OFF_BE2 + fragpos(k, c, 128)] = bfc(Wbe2[u]);
    } else if (t < OFF_D1) {
        int u = t - OFF_BE3;  int k = u >> 7, c = u & 127;
        ws[OFF_BE3 + fragpos(k, c, 128)] = bfc(Wbe3[u]);
    } else if (t < OFF_D2) {
        int u = t - OFF_D1;   int k = u >> 8, c = u & 255;
        ws[OFF_D1 + fragpos(k, c, 256)] = bfc(Wd1[u]);
    } else if (t < OFF_F1) {
        int u = t - OFF_D2;   int k = u >> 8, c = u & 255;
        ws[OFF_D2 + fragpos(k, c, 256)] = bfc(Wd2[u]);
    } else if (t < OFF_F2) {                  // f1 rows 0..383 only
        int u = t - OFF_F1;   int k = u >> 8, c = u & 255;
        ws[OFF_F1 + fragpos(k, c, 256)] = bfc(Wf1[u]);
    } else {
        int u = t - OFF_F2;   int k = u >> 8, c = u & 255;
        ws[OFF_F2 + fragpos(k, c, 256)] = bfc(Wf2[u]);
    }
}

__global__ void __launch_bounds__(256)
prep_n(const float* __restrict__ src, uint16_t* __restrict__ dst, int n){
    int t = blockIdx.x * 256 + threadIdx.x;
    if (t < n) dst[t] = bfc(src[t]);
}

// ---------------- async global->LDS helper ----------------
typedef const __attribute__((address_space(1))) void gas_void;
typedef __attribute__((address_space(3))) void las_void;
__device__ __forceinline__ void g2l16(const void* g, void* l){
    __builtin_amdgcn_global_load_lds((gas_void*)g, (las_void*)l, 16, 0, 0);
}

// LDS (135168 B, 1 block/CU, 512 threads = 8 waves = 2 waves/SIMD):
//   [0      .. 32768)  bufE : bf16[128][128] XOR-swz
//   [32768  .. 98304)  h256 : bf16[128][256] XOR-swz
//   [98304  ..131072)  wbuf : 2 x 16KB weight-frag chunk (double buffer)
//   [131072 ..135168)  misc : ps[128] pd[128] sidx[128] didx[128] dpp[2][128] bop[2][128]
#define LDS_TOTAL 135168

// ==================== FAST kernel: prepacked bf16 weights via global_load_lds ====================
__global__ void __launch_bounds__(512) __attribute__((amdgpu_waves_per_eu(2, 2)))
bond_fast_kernel(const int* __restrict__ edge_index,
                 const float* __restrict__ edge_attr, const float* __restrict__ dual_emb,
                 const float* __restrict__ logits,
                 const float* __restrict__ b_be1, const float* __restrict__ g_be1, const float* __restrict__ bb_be1,
                 const float* __restrict__ b_be2, const float* __restrict__ g_be2, const float* __restrict__ bb_be2,
                 const float* __restrict__ b_be3, const float* __restrict__ g_be3, const float* __restrict__ bb_be3,
                 const float* __restrict__ b_d1, const float* __restrict__ b_d2,
                 const float* __restrict__ W_do, const float* __restrict__ b_do,
                 const float* __restrict__ W_f1, const float* __restrict__ b_f1,
                 const float* __restrict__ b_f2,
                 const float* __restrict__ W_bo, const float* __restrict__ b_bo,
                 const uint16_t* __restrict__ ws, float* __restrict__ out, int E)
{
    __shared__ char lds[LDS_TOTAL];
    const int t    = threadIdx.x;
    const int wave = t >> 6;
    const int lane = t & 63;
    const int li   = lane & 15, lg = lane >> 4;
    const int eg   = wave >> 1;
    const int ch   = wave & 1;
    const int e0b  = blockIdx.x * 128;

    char* bufE = lds;
    char* h256 = lds + 32768;
    uint16_t* wb0 = (uint16_t*)(lds + 98304);
    uint16_t* wb1 = (uint16_t*)(lds + 114688);
    float* ps  = (float*)(lds + 131072);
    float* pd  = (float*)(lds + 131584);
    int* sidx  = (int*)(lds + 132096);
    int* didx  = (int*)(lds + 132608);
    float* dpp = (float*)(lds + 133120);
    float* bop = (float*)(lds + 134144);

    const uint8_t*  wsb = (const uint8_t*)ws;
    const uint16_t* nbf = ws + WS_ELEMS;      // node_emb bf16 [N][128]

    if (t < 128) {
        int e = e0b + t; if (e >= E) e = E - 1;
        int s_ = edge_index[e];
        int d_ = edge_index[E + e];
        sidx[t] = s_; didx[t] = d_;
        ps[t] = fsigmoid(logits[s_]);
        pd[t] = fsigmoid(logits[d_]);
    }

    int cur = 0;
    // stage next chunk into the NOT-current buffer (prev step's reads done at last barrier)
    auto stageW = [&](int elemoff, int big){
        uint8_t* dst = (uint8_t*)(cur ? wb0 : wb1) + t * 16;
        const uint8_t* g = wsb + (size_t)elemoff * 2 + t * 16;
        g2l16(g, dst);
        if (big) g2l16(g + 8192, dst + 8192);
    };
    auto stepend = [&](){ __syncthreads(); cur ^= 1; };
    auto curbuf  = [&]() -> const uint16_t* { return cur ? wb1 : wb0; };

    f32x4 acc[2][8];

    auto ldf = [&](const uint16_t* w, int fid) -> bf16x8 {
        return *(const bf16x8*)(w + fid * 512 + lane * 8);
    };
    auto grpBE = [&](const uint16_t* w, bf16x8 a0){
        #pragma unroll
        for (int ct = 0; ct < 8; ++ct){
            bf16x8 b = ldf(w, ct);
            acc[0][ct] = __builtin_amdgcn_mfma_f32_16x16x32_bf16(a0, b, acc[0][ct], 0, 0, 0);
        }
    };
    auto grp256 = [&](const uint16_t* w, bf16x8 a0, bf16x8 a1){
        #pragma unroll
        for (int ct = 0; ct < 8; ++ct){
            bf16x8 b = ldf(w, ch * 8 + ct);
            acc[0][ct] = __builtin_amdgcn_mfma_f32_16x16x32_bf16(a0, b, acc[0][ct], 0, 0, 0);
            acc[1][ct] = __builtin_amdgcn_mfma_f32_16x16x32_bf16(a1, b, acc[1][ct], 0, 0, 0);
        }
    };
    auto initBE = [&](const float* b){
        #pragma unroll
        for (int ct = 0; ct < 8; ++ct){
            float bv = b[li + 16 * ct];
            f32x4 iv = {bv, bv, bv, bv};
            acc[0][ct] = iv;
        }
    };
    auto init256 = [&](const float* b){
        #pragma unroll
        for (int ct = 0; ct < 8; ++ct){
            float bv = b[ch * 128 + ct * 16 + li];
            f32x4 iv = {bv, bv, bv, bv};
            acc[0][ct] = iv; acc[1][ct] = iv;
        }
    };
    auto eb_read = [&](int row, int kt) -> bf16x8 {
        int off = row * 256 + (kt * 32 + lg * 8) * 2;
        return *(const bf16x8*)(bufE + (off ^ ((row & 7) << 4)));
    };
    auto h2_read = [&](int row, int kt) -> bf16x8 {
        int off = row * 512 + (kt * 32 + lg * 8) * 2;
        return *(const bf16x8*)(h256 + (off ^ ((row & 7) << 4)));
    };
    auto lnstoreBE = [&](const float* g, const float* bb){
        #pragma unroll
        for (int r = 0; r < 4; ++r){
            float s = 0.f, q = 0.f;
            #pragma unroll
            for (int ct = 0; ct < 8; ++ct){ float v = acc[0][ct][r]; s += v; q += v*v; }
            s += __shfl_xor(s, 1); q += __shfl_xor(q, 1);
            s += __shfl_xor(s, 2); q += __shfl_xor(q, 2);
            s += __shfl_xor(s, 4); q += __shfl_xor(q, 4);
            s += __shfl_xor(s, 8); q += __shfl_xor(q, 8);
            float mu = s * 0.0078125f;
            float var = q * 0.0078125f - mu * mu;
            float rs = rsqrtf(var + 1e-5f);
            int row = wave * 16 + lg * 4 + r;
            int rswz = (row & 7) << 4;
            #pragma unroll
            for (int ct = 0; ct < 8; ++ct){
                int col = li + 16 * ct;
                float v = (acc[0][ct][r] - mu) * rs * g[col] + bb[col];
                int off = row * 256 + col * 2;
                *(uint16_t*)(bufE + (off ^ rswz)) = bfc(fsilu(v));
            }
        }
    };
    auto silustore256 = [&](){
        #pragma unroll
        for (int rt = 0; rt < 2; ++rt){
            #pragma unroll
            for (int r = 0; r < 4; ++r){
                int row = eg * 32 + rt * 16 + lg * 4 + r;
                int rswz = (row & 7) << 4;
                #pragma unroll
                for (int ct = 0; ct < 8; ++ct){
                    int off = row * 512 + (ch * 128 + ct * 16 + li) * 2;
                    *(uint16_t*)(h256 + (off ^ rswz)) = bfc(fsilu(acc[rt][ct][r]));
                }
            }
        }
    };

    // ---- prologue: stage BE1 chunk into wb0 ----
    {
        const uint8_t* g = wsb + t * 16;                 // OFF_BE1 = 0, 8KB
        g2l16(g, (uint8_t*)wb0 + t * 16);
    }
    __syncthreads();   // cur = 0 -> read wb0, stage wb1

    // ---- g0: BE1 ----
    {
        stageW(OFF_BE2, 0);
        bf16x8 aE = {0,0,0,0,0,0,0,0};
        if (lg < 2){
            int ea = e0b + wave * 16 + li; if (ea >= E) ea = E - 1;
            const float* pa = edge_attr + (size_t)ea * 16 + lg * 8;
            aE = pack8(*(const float4v*)pa, *(const float4v*)(pa + 4));
        }
        initBE(b_be1);
        grpBE(curbuf(), aE);
        lnstoreBE(g_be1, bb_be1);
        stepend();
    }

    // ---- g1..4: BE2 ----
    initBE(b_be2);
    #pragma unroll 1
    for (int kt = 0; kt < 4; ++kt){
        if (kt < 3) stageW(OFF_BE2 + (kt + 1) * 4096, 0);
        else        stageW(OFF_BE3, 0);
        grpBE(curbuf(), eb_read(wave * 16 + li, kt));
        if (kt == 3) lnstoreBE(g_be2, bb_be2);
        stepend();
    }
    // ---- g5..8: BE3 ----
    initBE(b_be3);
    #pragma unroll 1
    for (int kt = 0; kt < 4; ++kt){
        if (kt < 3) stageW(OFF_BE3 + (kt + 1) * 4096, 0);
        else        stageW(OFF_D1, 1);
        grpBE(curbuf(), eb_read(wave * 16 + li, kt));
        if (kt == 3) lnstoreBE(g_be3, bb_be3);       // e3 stays in bufE
        stepend();
    }

    // ---- g9..12: D1 (128 -> 256), A from dual_emb f32 ----
    init256(b_d1);
    #pragma unroll 1
    for (int kt = 0; kt < 4; ++kt){
        float4v va0, va1, vb0, vb1;
        {
            int ea = e0b + eg * 32 + li;      if (ea >= E) ea = E - 1;
            int eb = e0b + eg * 32 + 16 + li; if (eb >= E) eb = E - 1;
            const float* pa = dual_emb + (size_t)ea * 128 + kt * 32 + lg * 8;
            const float* pb = dual_emb + (size_t)eb * 128 + kt * 32 + lg * 8;
            va0 = *(const float4v*)pa; va1 = *(const float4v*)(pa + 4);
            vb0 = *(const float4v*)pb; vb1 = *(const float4v*)(pb + 4);
        }
        if (kt < 3) stageW(OFF_D1 + (kt + 1) * 8192, 1);
        else        stageW(OFF_D2, 1);
        grp256(curbuf(), pack8(va0, va1), pack8(vb0, vb1));
        if (kt == 3) silustore256();
        stepend();
    }

    // ---- g13..20: D2 + W_do partial dot ----
    init256(b_d2);
    #pragma unroll 1
    for (int kt = 0; kt < 8; ++kt){
        if (kt < 7) stageW(OFF_D2 + (kt + 1) * 8192, 1);
        else        stageW(OFF_F1, 1);
        grp256(curbuf(), h2_read(eg * 32 + li, kt), h2_read(eg * 32 + 16 + li, kt));
        if (kt == 7){
            #pragma unroll
            for (int rt = 0; rt < 2; ++rt){
                #pragma unroll
                for (int r = 0; r < 4; ++r){
                    float s = 0.f;
                    #pragma unroll
                    for (int ct = 0; ct < 8; ++ct)
                        s += fsilu(acc[rt][ct][r]) * W_do[ch * 128 + ct * 16 + li];
                    s += __shfl_xor(s, 1); s += __shfl_xor(s, 2);
                    s += __shfl_xor(s, 4); s += __shfl_xor(s, 8);
                    if (li == 0) dpp[ch * 128 + eg * 32 + rt * 16 + lg * 4 + r] = s;
                }
            }
        }
        stepend();
    }

    // ---- g21..32: F1 (387 -> 256), A-node from prepacked bf16 ----
    {
        {
            float bdo0 = b_do[0];
            #pragma unroll
            for (int ct = 0; ct < 8; ++ct){
                int col = ch * 128 + ct * 16 + li;
                float bv = b_f1[col];
                float t0 = W_f1[384 * 256 + col];
                float t1 = W_f1[385 * 256 + col];
                float t2 = W_f1[386 * 256 + col];
                #pragma unroll
                for (int rt = 0; rt < 2; ++rt)
                    #pragma unroll
                    for (int r = 0; r < 4; ++r){
                        int row = eg * 32 + rt * 16 + lg * 4 + r;
                        float dv = fsigmoid(dpp[row] + dpp[128 + row] + bdo0);
                        acc[rt][ct][r] = bv + dv*t0 + ps[row]*t1 + pd[row]*t2;
                    }
            }
        }
        int s0 = sidx[eg * 32 + li],      s1 = sidx[eg * 32 + 16 + li];
        int d0 = didx[eg * 32 + li],      d1 = didx[eg * 32 + 16 + li];
        #pragma unroll 1
        for (int kt = 0; kt < 12; ++kt){
            bf16x8 a0, a1;
            if (kt < 8){
                int ra = (kt < 4) ? s0 : d0;
                int rb = (kt < 4) ? s1 : d1;
                int ko = (kt & 3) * 32 + lg * 8;
                a0 = *(const bf16x8*)(nbf + (size_t)ra * 128 + ko);
                a1 = *(const bf16x8*)(nbf + (size_t)rb * 128 + ko);
            } else {
                a0 = eb_read(eg * 32 + li, kt - 8);
                a1 = eb_read(eg * 32 + 16 + li, kt - 8);
            }
            if (kt < 11) stageW(OFF_F1 + (kt + 1) * 8192, 1);
            else         stageW(OFF_F2, 1);
            grp256(curbuf(), a0, a1);
            if (kt == 11) silustore256();
            stepend();
        }
    }

    // ---- g33..40: F2 + W_bo partial dot -> out ----
    init256(b_f2);
    #pragma unroll 1
    for (int kt = 0; kt < 8; ++kt){
        if (kt < 7) stageW(OFF_F2 + (kt + 1) * 8192, 1);
        grp256(curbuf(), h2_read(eg * 32 + li, kt), h2_read(eg * 32 + 16 + li, kt));
        if (kt == 7){
            #pragma unroll
            for (int rt = 0; rt < 2; ++rt){
                #pragma unroll
                for (int r = 0; r < 4; ++r){
                    float s = 0.f;
                    #pragma unroll
                    for (int ct = 0; ct < 8; ++ct)
                        s += fsilu(acc[rt][ct][r]) * W_bo[ch * 128 + ct * 16 + li];
                    s += __shfl_xor(s, 1); s += __shfl_xor(s, 2);
                    s += __shfl_xor(s, 4); s += __shfl_xor(s, 8);
                    if (li == 0) bop[ch * 128 + eg * 32 + rt * 16 + lg * 4 + r] = s;
                }
            }
        } else {
            stepend();
        }
    }
    __syncthreads();
    if (t < 128){
        int e = e0b + t;
        if (e < E) out[e] = bop[t] + bop[128 + t] + b_bo[0];
    }
}

// ==================== FALLBACK kernel: R6 (self-contained, no ws) ====================
__global__ void __launch_bounds__(512) __attribute__((amdgpu_waves_per_eu(2, 2)))
bond_fused_kernel(const float* __restrict__ node_emb, const int* __restrict__ edge_index,
                  const float* __restrict__ edge_attr, const float* __restrict__ dual_emb,
                  const float* __restrict__ logits,
                  const float* __restrict__ W_be1, const float* __restrict__ b_be1,
                  const float* __restrict__ g_be1, const float* __restrict__ bb_be1,
                  const float* __restrict__ W_be2, const float* __restrict__ b_be2,
                  const float* __restrict__ g_be2, const float* __restrict__ bb_be2,
                  const float* __restrict__ W_be3, const float* __restrict__ b_be3,
                  const float* __restrict__ g_be3, const float* __restrict__ bb_be3,
                  const float* __restrict__ W_d1, const float* __restrict__ b_d1,
                  const float* __restrict__ W_d2, const float* __restrict__ b_d2,
                  const float* __restrict__ W_do, const float* __restrict__ b_do,
                  const float* __restrict__ W_f1, const float* __restrict__ b_f1,
                  const float* __restrict__ W_f2, const float* __restrict__ b_f2,
                  const float* __restrict__ W_bo, const float* __restrict__ b_bo,
                  float* __restrict__ out, int E)
{
    __shared__ char lds[LDS_TOTAL];
    const int t    = threadIdx.x;
    const int wave = t >> 6;
    const int lane = t & 63;
    const int li   = lane & 15, lg = lane >> 4;
    const int eg   = wave >> 1;
    const int ch   = wave & 1;
    const int e0b  = blockIdx.x * 128;

    char* bufE = lds;
    char* h256 = lds + 32768;
    uint16_t* wb0 = (uint16_t*)(lds + 98304);
    uint16_t* wb1 = (uint16_t*)(lds + 114688);
    float* ps  = (float*)(lds + 131072);
    float* pd  = (float*)(lds + 131584);
    int* sidx  = (int*)(lds + 132096);
    int* didx  = (int*)(lds + 132608);
    float* dpp = (float*)(lds + 133120);
    float* bop = (float*)(lds + 134144);

    if (t < 128) {
        int e = e0b + t; if (e >= E) e = E - 1;
        int s_ = edge_index[e];
        int d_ = edge_index[E + e];
        sidx[t] = s_; didx[t] = d_;
        ps[t] = fsigmoid(logits[s_]);
        pd[t] = fsigmoid(logits[d_]);
    }

    float sr[2][8];
    auto issueW256 = [&](const float* W, int kbase){
        #pragma unroll
        for (int h = 0; h < 2; ++h){
            const float* p = W + (size_t)(kbase + lg * 8) * 256 + (wave + 8*h) * 16 + li;
            #pragma unroll
            for (int j = 0; j < 8; ++j) sr[h][j] = p[j * 256];
        }
    };
    auto issueW128 = [&](const float* W, int kbase, int K){
        const float* p = W + (size_t)(kbase + lg * 8) * 128 + wave * 16 + li;
        #pragma unroll
        for (int j = 0; j < 8; ++j)
            sr[0][j] = (kbase + lg * 8 + j < K) ? p[j * 128] : 0.f;
    };
    auto commitW = [&](uint16_t* dst, int nh){
        #pragma unroll
        for (int h = 0; h < 2; ++h){
            if (h < nh){
                uint4 w;
                w.x = pk2(sr[h][0], sr[h][1]); w.y = pk2(sr[h][2], sr[h][3]);
                w.z = pk2(sr[h][4], sr[h][5]); w.w = pk2(sr[h][6], sr[h][7]);
                *(uint4*)(dst + (wave + 8*h) * 512 + lane * 8) = w;
            }
        }
    };

    int cur = 0;
    auto stepend = [&](int mode){
        if (mode) commitW(cur ? wb0 : wb1, mode == 128 ? 1 : 2);
        __syncthreads();
        cur ^= 1;
    };
    auto curbuf = [&]() -> const uint16_t* { return cur ? wb1 : wb0; };

    f32x4 acc[2][8];

    auto ldf = [&](const uint16_t* w, int fid) -> bf16x8 {
        return *(const bf16x8*)(w + fid * 512 + lane * 8);
    };
    auto grpBE = [&](const uint16_t* w, bf16x8 a0){
        #pragma unroll
        for (int ct = 0; ct < 8; ++ct){
            bf16x8 b = ldf(w, ct);
            acc[0][ct] = __builtin_amdgcn_mfma_f32_16x16x32_bf16(a0, b, acc[0][ct], 0, 0, 0);
        }
    };
    auto grp256 = [&](const uint16_t* w, bf16x8 a0, bf16x8 a1){
        #pragma unroll
        for (int ct = 0; ct < 8; ++ct){
            bf16x8 b = ldf(w, ch * 8 + ct);
            acc[0][ct] = __builtin_amdgcn_mfma_f32_16x16x32_bf16(a0, b, acc[0][ct], 0, 0, 0);
            acc[1][ct] = __builtin_amdgcn_mfma_f32_16x16x32_bf16(a1, b, acc[1][ct], 0, 0, 0);
        }
    };
    auto initBE = [&](const float* b){
        #pragma unroll
        for (int ct = 0; ct < 8; ++ct){
            float bv = b[li + 16 * ct];
            f32x4 iv = {bv, bv, bv, bv};
            acc[0][ct] = iv;
        }
    };
    auto init256 = [&](const float* b){
        #pragma unroll
        for (int ct = 0; ct < 8; ++ct){
            float bv = b[ch * 128 + ct * 16 + li];
            f32x4 iv = {bv, bv, bv, bv};
            acc[0][ct] = iv; acc[1][ct] = iv;
        }
    };
    auto eb_read = [&](int row, int kt) -> bf16x8 {
        int off = row * 256 + (kt * 32 + lg * 8) * 2;
        return *(const bf16x8*)(bufE + (off ^ ((row & 7) << 4)));
    };
    auto h2_read = [&](int row, int kt) -> bf16x8 {
        int off = row * 512 + (kt * 32 + lg * 8) * 2;
        return *(const bf16x8*)(h256 + (off ^ ((row & 7) << 4)));
    };
    auto lnstoreBE = [&](const float* g, const float* bb){
        #pragma unroll
        for (int r = 0; r < 4; ++r){
            float s = 0.f, q = 0.f;
            #pragma unroll
            for (int ct = 0; ct < 8; ++ct){ float v = acc[0][ct][r]; s += v; q += v*v; }
            s += __shfl_xor(s, 1); q += __shfl_xor(q, 1);
            s += __shfl_xor(s, 2); q += __shfl_xor(q, 2);
            s += __shfl_xor(s, 4); q += __shfl_xor(q, 4);
            s += __shfl_xor(s, 8); q += __shfl_xor(q, 8);
            float mu = s * 0.0078125f;
            float var = q * 0.0078125f - mu * mu;
            float rs = rsqrtf(var + 1e-5f);
            int row = wave * 16 + lg * 4 + r;
            int rswz = (row & 7) << 4;
            #pragma unroll
            for (int ct = 0; ct < 8; ++ct){
                int col = li + 16 * ct;
                float v = (acc[0][ct][r] - mu) * rs * g[col] + bb[col];
                int off = row * 256 + col * 2;
                *(uint16_t*)(bufE + (off ^ rswz)) = bfc(fsilu(v));
            }
        }
    };
    auto silustore256 = [&](){
        #pragma unroll
        for (int rt = 0; rt < 2; ++rt){
            #pragma unroll
            for (int r = 0; r < 4; ++r){
                int row = eg * 32 + rt * 16 + lg * 4 + r;
                int rswz = (row & 7) << 4;
                #pragma unroll
                for (int ct = 0; ct < 8; ++ct){
                    int off = row * 512 + (ch * 128 + ct * 16 + li) * 2;
                    *(uint16_t*)(h256 + (off ^ rswz)) = bfc(fsilu(acc[rt][ct][r]));
                }
            }
        }
    };

    issueW128(W_be1, 0, 16);
    commitW(wb0, 1);
    __syncthreads();

    {
        bf16x8 aE = {0,0,0,0,0,0,0,0};
        if (lg < 2){
            int ea = e0b + wave * 16 + li; if (ea >= E) ea = E - 1;
            const float* pa = edge_attr + (size_t)ea * 16 + lg * 8;
            aE = pack8(*(const float4v*)pa, *(const float4v*)(pa + 4));
        }
        issueW128(W_be2, 0, 128);
        initBE(b_be1);
        grpBE(curbuf(), aE);
        lnstoreBE(g_be1, bb_be1);
        stepend(128);
    }

    initBE(b_be2);
    #pragma unroll 1
    for (int kt = 0; kt < 4; ++kt){
        if (kt < 3) issueW128(W_be2, (kt + 1) * 32, 128);
        else        issueW128(W_be3, 0, 128);
        grpBE(curbuf(), eb_read(wave * 16 + li, kt));
        if (kt == 3) lnstoreBE(g_be2, bb_be2);
        stepend(128);
    }
    initBE(b_be3);
    #pragma unroll 1
    for (int kt = 0; kt < 4; ++kt){
        if (kt < 3) issueW128(W_be3, (kt + 1) * 32, 128);
        else        issueW256(W_d1, 0);
        grpBE(curbuf(), eb_read(wave * 16 + li, kt));
        if (kt == 3) lnstoreBE(g_be3, bb_be3);
        stepend(kt < 3 ? 128 : 256);
    }

    init256(b_d1);
    #pragma unroll 1
    for (int kt = 0; kt < 4; ++kt){
        float4v va0, va1, vb0, vb1;
        {
            int ea = e0b + eg * 32 + li;      if (ea >= E) ea = E - 1;
            int eb = e0b + eg * 32 + 16 + li; if (eb >= E) eb = E - 1;
            const float* pa = dual_emb + (size_t)ea * 128 + kt * 32 + lg * 8;
            const float* pb = dual_emb + (size_t)eb * 128 + kt * 32 + lg * 8;
            va0 = *(const float4v*)pa; va1 = *(const float4v*)(pa + 4);
            vb0 = *(const float4v*)pb; vb1 = *(const float4v*)(pb + 4);
        }
        if (kt < 3) issueW256(W_d1, (kt + 1) * 32);
        else        issueW256(W_d2, 0);
        grp256(curbuf(), pack8(va0, va1), pack8(vb0, vb1));
        if (kt == 3) silustore256();
        stepend(256);
    }

    init256(b_d2);
    #pragma unroll 1
    for (int kt = 0; kt < 8; ++kt){
        if (kt < 7) issueW256(W_d2, (kt + 1) * 32);
        else        issueW256(W_f1, 0);
        grp256(curbuf(), h2_read(eg * 32 + li, kt), h2_read(eg * 32 + 16 + li, kt));
        if (kt == 7){
            #pragma unroll
            for (int rt = 0; rt < 2; ++rt){
                #pragma unroll
                for (int r = 0; r < 4; ++r){
                    float s = 0.f;
                    #pragma unroll
                    for (int ct = 0; ct < 8; ++ct)
                        s += fsilu(acc[rt][ct][r]) * W_do[ch * 128 + ct * 16 + li];
                    s += __shfl_xor(s, 1); s += __shfl_xor(s, 2);
                    s += __shfl_xor(s, 4); s += __shfl_xor(s, 8);
                    if (li == 0) dpp[ch * 128 + eg * 32 + rt * 16 + lg * 4 + r] = s;
                }
            }
        }
        stepend(256);
    }

    {
        {
            float bdo0 = b_do[0];
            #pragma unroll
            for (int ct = 0; ct < 8; ++ct){
                int col = ch * 128 + ct * 16 + li;
                float bv = b_f1[col];
                float t0 = W_f1[384 * 256 + col];
                float t1 = W_f1[385 * 256 + col];
                float t2 = W_f1[386 * 256 + col];
                #pragma unroll
                for (int rt = 0; rt < 2; ++rt)
                    #pragma unroll
                    for (int r = 0; r < 4; ++r){
                        int row = eg * 32 + rt * 16 + lg * 4 + r;
                        float dv = fsigmoid(dpp[row] + dpp[128 + row] + bdo0);
                        acc[rt][ct][r] = bv + dv*t0 + ps[row]*t1 + pd[row]*t2;
                    }
            }
        }
        int s0 = sidx[eg * 32 + li],      s1 = sidx[eg * 32 + 16 + li];
        int d0 = didx[eg * 32 + li],      d1 = didx[eg * 32 + 16 + li];
        #pragma unroll 1
        for (int kt = 0; kt < 12; ++kt){
            bf16x8 a0, a1;
            if (kt < 8){
                int ra = (kt < 4) ? s0 : d0;
                int rb = (kt < 4) ? s1 : d1;
                int ko = (kt & 3) * 32 + lg * 8;
                const float* pa = node_emb + (size_t)ra * 128 + ko;
                const float* pb = node_emb + (size_t)rb * 128 + ko;
                a0 = pack8(*(const float4v*)pa, *(const float4v*)(pa + 4));
                a1 = pack8(*(const float4v*)pb, *(const float4v*)(pb + 4));
            } else {
                a0 = eb_read(eg * 32 + li, kt - 8);
                a1 = eb_read(eg * 32 + 16 + li, kt - 8);
            }
            if (kt < 11) issueW256(W_f1, (kt + 1) * 32);
            else         issueW256(W_f2, 0);
            grp256(curbuf(), a0, a1);
            if (kt == 11) silustore256();
            stepend(256);
        }
    }

    init256(b_f2);
    #pragma unroll 1
    for (int kt = 0; kt < 8; ++kt){
        if (kt < 7) issueW256(W_f2, (kt + 1) * 32);
        grp256(curbuf(), h2_read(eg * 32 + li, kt), h2_read(eg * 32 + 16 + li, kt));
        if (kt == 7){
            #pragma unroll
            for (int rt = 0; rt < 2; ++rt){
                #pragma unroll
                for (int r = 0; r < 4; ++r){
                    float s = 0.f;
                    #pragma unroll
                    for (int ct = 0; ct < 8; ++ct)
                        s += fsilu(acc[rt][ct][r]) * W_bo[ch * 128 + ct * 16 + li];
                    s += __shfl_xor(s, 1); s += __shfl_xor(s, 2);
                    s += __shfl_xor(s, 4); s += __shfl_xor(s, 8);
                    if (li == 0) bop[ch * 128 + eg * 32 + rt * 16 + lg * 4 + r] = s;
                }
            }
        } else {
            stepend(256);
        }
    }
    __syncthreads();
    if (t < 128){
        int e = e0b + t;
        if (e < E) out[e] = bop[t] + bop[128 + t] + b_bo[0];
    }
}

extern "C" void kernel_launch(void* const* d_in, const int* in_sizes, int n_in,
                              void* d_out, int out_size, void* d_ws, size_t ws_size,
                              hipStream_t stream) {
    const float* node_emb   = (const float*)d_in[0];
    const int*   edge_index = (const int*)d_in[1];
    const float* edge_attr  = (const float*)d_in[2];
    const float* dual_emb   = (const float*)d_in[3];
    const float* logits     = (const float*)d_in[4];
    const float* W_be1 = (const float*)d_in[5];
    const float* b_be1 = (const float*)d_in[6];
    const float* g_be1 = (const float*)d_in[7];
    const float* bb_be1= (const float*)d_in[8];
    const float* W_be2 = (const float*)d_in[9];
    const float* b_be2 = (const float*)d_in[10];
    const float* g_be2 = (const float*)d_in[11];
    const float* bb_be2= (const float*)d_in[12];
    const float* W_be3 = (const float*)d_in[13];
    const float* b_be3 = (const float*)d_in[14];
    const float* g_be3 = (const float*)d_in[15];
    const float* bb_be3= (const float*)d_in[16];
    const float* W_d1  = (const float*)d_in[17];
    const float* b_d1  = (const float*)d_in[18];
    const float* W_d2  = (const float*)d_in[19];
    const float* b_d2  = (const float*)d_in[20];
    const float* W_do  = (const float*)d_in[21];
    const float* b_do  = (const float*)d_in[22];
    const float* W_f1  = (const float*)d_in[23];
    const float* b_f1  = (const float*)d_in[24];
    const float* W_f2  = (const float*)d_in[25];
    const float* b_f2  = (const float*)d_in[26];
    const float* W_bo  = (const float*)d_in[27];
    const float* b_bo  = (const float*)d_in[28];
    float* out = (float*)d_out;

    int E = in_sizes[2] / 16;
    int nblocks = (E + 127) / 128;
    size_t nodeElems = (size_t)in_sizes[0];
    size_t wsNeed = ((size_t)WS_ELEMS + nodeElems) * 2;

    if (ws_size >= wsNeed) {
        uint16_t* ws16 = (uint16_t*)d_ws;
        prep_w<<<dim3((WS_ELEMS + 255) / 256), dim3(256), 0, stream>>>(
            W_be1, W_be2, W_be3, W_d1, W_d2, W_f1, W_f2, ws16);
        prep_n<<<dim3((int)((nodeElems + 255) / 256)), dim3(256), 0, stream>>>(
            node_emb, ws16 + WS_ELEMS, (int)nodeElems);
        bond_fast_kernel<<<dim3(nblocks), dim3(512), 0, stream>>>(
            edge_index, edge_attr, dual_emb, logits,
            b_be1, g_be1, bb_be1,
            b_be2, g_be2, bb_be2,
            b_be3, g_be3, bb_be3,
            b_d1, b_d2, W_do, b_do,
            W_f1, b_f1, b_f2, W_bo, b_bo,
            ws16, out, E);
    } else {
        bond_fused_kernel<<<dim3(nblocks), dim3(512), 0, stream>>>(
            node_emb, edge_index, edge_attr, dual_emb, logits,
            W_be1, b_be1, g_be1, bb_be1,
            W_be2, b_be2, g_be2, bb_be2,
            W_be3, b_be3, g_be3, bb_be3,
            W_d1, b_d1, W_d2, b_d2, W_do, b_do,
            W_f1, b_f1, W_f2, b_f2, W_bo, b_bo,
            out, E);
    }
}